// Round 10
// baseline (1029.588 us; speedup 1.0000x reference)
//
#include <hip/hip_runtime.h>

// ---------------------------------------------------------------------------
// ScepterVisionTransformer forward on MI355X (gfx950).
// R20:
//  * flash_attn: occupancy push. R19 counters: occupancy 16.8% (5.4 waves/CU)
//    with VALU 45 / MFMA 16 -> stall-bound, grid-limited (912 blocks =
//    3.56/CU). (a) Plds halved to one per-wave [16x72] buffer reused across
//    both t-phases (per-wave DS ordering makes this safe) -> LDS 25.6KB;
//    (b) K-split 2 -> 3 -> 1368 blocks = 5.34/CU, co-resident at VGPR cap
//    5 blocks/CU (~20 waves/CU = 1.4x latency hiding). Combine sums 3.
//  * gemm_bt: unchanged from R19 (128x64 tile, reg-staged pipeline).
// ---------------------------------------------------------------------------

#define AS1 __attribute__((address_space(1)))
#define AS3 __attribute__((address_space(3)))

using bf16 = __bf16;
typedef __bf16 bf16x8 __attribute__((ext_vector_type(8)));
typedef float  f32x4  __attribute__((ext_vector_type(4)));

#define CDIV(a, b) (((a) + (b) - 1) / (b))

// DPP row_ror within 16-lane row
template <int SH>
__device__ __forceinline__ float rorf(float x) {
  int i = __builtin_amdgcn_update_dpp(0, __builtin_bit_cast(int, x),
                                      0x120 + SH, 0xF, 0xF, false);
  return __builtin_bit_cast(float, i);
}
__device__ __forceinline__ float rowsum16(float v) {
  v += rorf<1>(v); v += rorf<2>(v); v += rorf<4>(v); v += rorf<8>(v);
  return v;
}

// ---------------------------------------------------------------------------
// Generic GEMM: C(MxN) = A(MxK) * B^T (B stored N-major), bf16 in, fp32 acc.
// Tile 128x64, 4 waves (2M x 2N, each 64x32 out). Reg-staged pipeline:
// tile t+1 in VGPRs, compute t, then write t+1 to the alternate LDS buffer
// and issue loads for t+2. One raw barrier per K-step.
// ksplit>1: partials atomicAdd'ed into Cf (residual-carrying), bias on z==0.
// Qo!=null: qkv-repack epilogue — writes Q/K(scaled)/VT bf16 directly.
// ---------------------------------------------------------------------------
__global__ __launch_bounds__(256) void gemm_bt(
    const bf16* __restrict__ A, const bf16* __restrict__ B,
    float* Cf, bf16* Cb, const float* __restrict__ bias,
    const float* addp, int addmod, int rrelu,
    int M, int N, int K, int lda, int ldb, int ldc,
    long long sA, long long sB, long long sC, int ksplit,
    bf16* __restrict__ Qo, bf16* __restrict__ Ko, bf16* __restrict__ Vo) {
  __shared__ __align__(16) bf16 As[2][128 * 32];   // 8KB x2
  __shared__ __align__(16) bf16 Bs[2][64 * 32];    // 4KB x2  => 24KB total
  const int tid  = threadIdx.x;
  const int lane = tid & 63;
  const int wave = tid >> 6;
  const int wm = wave & 1;
  const int wn = wave >> 1;
  const int q  = lane >> 4;
  const int r  = lane & 15;

  // bijective XCD-aware swizzle of the flat tile index (m204 formula)
  const int nwg = gridDim.x * gridDim.y;
  int flat = blockIdx.y * gridDim.x + blockIdx.x;
  {
    const int qq = nwg >> 3, rr = nwg & 7;
    const int xcd = flat & 7, lid = flat >> 3;
    flat = (xcd < rr ? xcd * (qq + 1) : rr * (qq + 1) + (xcd - rr) * qq) + lid;
  }
  const int tm0 = (flat % gridDim.x) * 128;
  const int tn0 = (flat / gridDim.x) * 64;
  const int z   = blockIdx.z;

  const bf16* Ab = A + (ksplit > 1 ? 0 : (size_t)z * (size_t)sA);
  const bf16* Bb = B + (ksplit > 1 ? 0 : (size_t)z * (size_t)sB);
  int kb = 0, ke = K;
  if (ksplit > 1) {
    const int kc = ((K / ksplit + 31) / 32) * 32;
    kb = z * kc;
    ke = min(kb + kc, K);
  }
  const int nt = (ke - kb + 31) >> 5;

  const int arow0 = min(tm0 + (tid >> 2), M - 1);
  const int arow1 = min(tm0 + (tid >> 2) + 64, M - 1);
  const int brow0 = min(tn0 + (tid >> 2), N - 1);
  const int kcol  = (tid & 3) * 8;
  const bf16* ap0 = Ab + (size_t)arow0 * lda + kcol;
  const bf16* ap1 = Ab + (size_t)arow1 * lda + kcol;
  const bf16* bp0 = Bb + (size_t)brow0 * ldb + kcol;

  f32x4 acc[4][2];
#pragma unroll
  for (int mi = 0; mi < 4; ++mi)
#pragma unroll
    for (int ni = 0; ni < 2; ++ni) acc[mi][ni] = (f32x4){0.f, 0.f, 0.f, 0.f};

  // staged tile registers (one K-step: A 2x16B + B 1x16B per thread)
  bf16x8 rA0, rA1, rB0;
  auto loadT = [&](int t) {
    const int k0 = kb + (t << 5);
    rA0 = *(const bf16x8*)(ap0 + k0);
    rA1 = *(const bf16x8*)(ap1 + k0);
    rB0 = *(const bf16x8*)(bp0 + k0);
  };
  // LDS row-major [rows][32]; thread tid owns elems [tid*8, tid*8+8).
  auto writeT = [&](int buf) {
    *(bf16x8*)&As[buf][tid * 8]        = rA0;
    *(bf16x8*)&As[buf][2048 + tid * 8] = rA1;
    *(bf16x8*)&Bs[buf][tid * 8]        = rB0;
  };

  // prologue: tile 0 -> LDS[0] (exposed once), tile 1 -> regs
  loadT(0);
  writeT(0);
  if (nt > 1) loadT(1);

  for (int t = 0; t < nt; ++t) {
    const int cur = t & 1;
    // own ds ops drained, then block-wide barrier: LDS[cur] (written last
    // iter) visible; all waves done reading LDS[cur^1].
    asm volatile("s_waitcnt lgkmcnt(0)" ::: "memory");
    __builtin_amdgcn_sched_barrier(0);
    __builtin_amdgcn_s_barrier();
    asm volatile("" ::: "memory");
    bf16x8 af[4], bfr[2];
#pragma unroll
    for (int mi = 0; mi < 4; ++mi)
      af[mi] = *(const bf16x8*)&As[cur][(wm * 64 + mi * 16 + r) * 32 + q * 8];
#pragma unroll
    for (int ni = 0; ni < 2; ++ni)
      bfr[ni] = *(const bf16x8*)&Bs[cur][(wn * 32 + ni * 16 + r) * 32 + q * 8];
#pragma unroll
    for (int mi = 0; mi < 4; ++mi)
#pragma unroll
      for (int ni = 0; ni < 2; ++ni)
        acc[mi][ni] = __builtin_amdgcn_mfma_f32_16x16x32_bf16(
            af[mi], bfr[ni], acc[mi][ni], 0, 0, 0);
    // staging BELOW the MFMAs (compute-early/write-late)
    __builtin_amdgcn_sched_barrier(0);
    if (t + 1 < nt) {
      writeT(cur ^ 1);
      if (t + 2 < nt) loadT(t + 2);
    }
  }

  float* cf = Cf ? Cf + (ksplit > 1 ? 0 : (size_t)z * (size_t)sC) : nullptr;
  bf16*  cb = Cb ? Cb + (ksplit > 1 ? 0 : (size_t)z * (size_t)sC) : nullptr;
#pragma unroll
  for (int mi = 0; mi < 4; ++mi) {
    const int row0 = tm0 + wm * 64 + mi * 16 + q * 4;
#pragma unroll
    for (int ni = 0; ni < 2; ++ni) {
      const int col = tn0 + wn * 32 + ni * 16 + r;
      if (col >= N) continue;
      const float bv = bias ? bias[col] : 0.f;
#pragma unroll
      for (int reg = 0; reg < 4; ++reg) {
        const int rr = row0 + reg;
        if (rr >= M) continue;
        if (Qo) {
          const float v = acc[mi][ni][reg] + bv;
          const int which = col / 768;
          const int hh = (col % 768) >> 6;
          const int dd = col & 63;
          const int bb2 = rr / 2352;
          const int ss = rr - bb2 * 2352;
          const int inst = bb2 * 12 + hh;
          if (which == 0)
            Qo[((size_t)inst * 2432 + ss) * 64 + dd] = (bf16)v;
          else if (which == 1)
            Ko[((size_t)inst * 2368 + ss) * 64 + dd] = (bf16)(v * 0.18033688f);
          else
            Vo[((size_t)inst * 64 + dd) * 2368 + ss] = (bf16)v;
        } else if (ksplit > 1) {
          float v = acc[mi][ni][reg];
          if (z == 0) {
            v += bv;
            if (addp) v += addp[(size_t)(rr % addmod) * ldc + col];
          }
          atomicAdd(&cf[(size_t)rr * ldc + col], v);
        } else {
          float v = acc[mi][ni][reg] + bv;
          if (addp) v += addp[(size_t)(rr % addmod) * ldc + col];
          if (rrelu) v = (v >= 0.f) ? v : 0.4f * v;
          if (cf) cf[(size_t)rr * ldc + col] = v;
          else    cb[(size_t)rr * ldc + col] = (bf16)v;
        }
      }
    }
  }
}

// ---------------------------------------------------------------------------
// Flash attention (R20): one wave = 32 Q-rows; 3 K-splits (z=0..2, chunks
// 12/12/13) -> 1368 blocks = 5.34/CU co-resident at 25.6KB LDS + 100 VGPR
// (5 blocks/CU). Single per-wave P buffer reused across both t-phases
// (per-wave DS ordering guarantees write(t1) cannot pass read(t0)).
// T14 async reg-staged K/V; raw s_barrier + lgkmcnt fences; vmcnt never
// drained; l-reduction deferred.
// ---------------------------------------------------------------------------
__global__ __launch_bounds__(256) void flash_attn_split(
    const bf16* __restrict__ Qg, const bf16* __restrict__ Kg,
    const bf16* __restrict__ Vt, float* __restrict__ Opart,
    float* __restrict__ Lpart) {
  __shared__ __align__(16) bf16 Kl[64 * 64];      // 8KB, swizzled
  __shared__ __align__(16) bf16 Vl[64 * 64];      // 8KB, swizzled (rows = d)
  __shared__ __align__(16) bf16 Plds[4][16 * 72]; // 9KB: one buf per wave
  const int tid  = threadIdx.x;
  const int lane = tid & 63;
  const int wave = tid >> 6;
  const int q = lane >> 4, r = lane & 15;
  const int inst = blockIdx.y;
  const int z = blockIdx.z;
  const int rt_raw = blockIdx.x * 4 + wave;   // 0..75
  const int rt = min(rt_raw, 73);             // clamp: redundant compute, all
                                              // waves participate in barriers
  const int row0 = rt * 32;
  const int ch0 = (z * 37) / 3;               // 0, 12, 24
  const int ch1 = ((z + 1) * 37) / 3;         // 12, 24, 37
  const bf16* Qi = Qg + (size_t)inst * 2432 * 64;
  const bf16* Ki = Kg + (size_t)inst * 2368 * 64;
  const bf16* Vi = Vt + (size_t)inst * 64 * 2368;

  bf16x8 qf[2][2];
#pragma unroll
  for (int t = 0; t < 2; ++t) {
    qf[t][0] = *(const bf16x8*)&Qi[(size_t)(row0 + t * 16 + r) * 64 + q * 8];
    qf[t][1] = *(const bf16x8*)&Qi[(size_t)(row0 + t * 16 + r) * 64 + 32 + q * 8];
  }

  f32x4 O[2][4];
  float l[2][4];
#pragma unroll
  for (int t = 0; t < 2; ++t)
#pragma unroll
    for (int i = 0; i < 4; ++i) {
      O[t][i] = (f32x4){0.f, 0.f, 0.f, 0.f};
      l[t][i] = 0.f;
    }

  // ---- T14 reg-staging layout: thread -> (row srow, 16B-unit suc) and
  // (srow+32, suc); global src pre-swizzled so LDS stays linear.
  const int srow = tid >> 3;                 // 0..31
  const int suc  = tid & 7;                  // 0..7
  const int gu   = (suc ^ (srow & 7)) * 8;   // swizzled global unit (elems)
  bf16* const kd0 = &Kl[srow * 64 + suc * 8];
  bf16* const kd1 = &Kl[(srow + 32) * 64 + suc * 8];
  bf16* const vd0 = &Vl[srow * 64 + suc * 8];
  bf16* const vd1 = &Vl[(srow + 32) * 64 + suc * 8];
  const int swz = (r & 7);   // frag-read swizzle key (row & 7 == r & 7)

  bf16x8 kr0, kr1, vr0, vr1;
  auto loadKV = [&](int ch) {
    const size_t col0 = (size_t)ch * 64;
    kr0 = *(const bf16x8*)&Ki[(col0 + srow) * 64 + gu];
    kr1 = *(const bf16x8*)&Ki[(col0 + srow + 32) * 64 + gu];
    vr0 = *(const bf16x8*)&Vi[(size_t)srow * 2368 + col0 + gu];
    vr1 = *(const bf16x8*)&Vi[(size_t)(srow + 32) * 2368 + col0 + gu];
  };

  loadKV(ch0);   // prologue: chunk ch0 in flight
  for (int ch = ch0; ch < ch1; ++ch) {
    // barrier A: all waves done reading LDS for the previous chunk.
    asm volatile("s_waitcnt lgkmcnt(0)" ::: "memory");
    __builtin_amdgcn_sched_barrier(0);
    __builtin_amdgcn_s_barrier();
    asm volatile("" ::: "memory");
    // write staged regs -> LDS (compiler inserts vmcnt waits for reg deps;
    // those loads had a full compute phase to land)
    *(bf16x8*)kd0 = kr0;
    *(bf16x8*)kd1 = kr1;
    *(bf16x8*)vd0 = vr0;
    *(bf16x8*)vd1 = vr1;
    if (ch + 1 < ch1) loadKV(ch + 1);   // issue next chunk, stays in flight
    asm volatile("s_waitcnt lgkmcnt(0)" ::: "memory");
    __builtin_amdgcn_sched_barrier(0);
    // barrier B: all waves' ds_writes visible; vmcnt NOT drained
    __builtin_amdgcn_s_barrier();
    asm volatile("" ::: "memory");

    // frag reads from LDS (swizzled, conflict-free)
    bf16x8 kf0[4], kf1[4], vf0[4], vf1[4];
#pragma unroll
    for (int ct = 0; ct < 4; ++ct) {
      const int krow = ct * 16 + r;
      kf0[ct] = *(const bf16x8*)&Kl[krow * 64 + ((q ^ swz) * 8)];
      kf1[ct] = *(const bf16x8*)&Kl[krow * 64 + (((q + 4) ^ swz) * 8)];
      vf0[ct] = *(const bf16x8*)&Vl[krow * 64 + ((q ^ swz) * 8)];
      vf1[ct] = *(const bf16x8*)&Vl[krow * 64 + (((q + 4) ^ swz) * 8)];
    }

    // S = QK' (scale folded into K), both tiles
    f32x4 s[2][4];
#pragma unroll
    for (int ct = 0; ct < 4; ++ct) {
#pragma unroll
      for (int t = 0; t < 2; ++t) {
        f32x4 a = (f32x4){0.f, 0.f, 0.f, 0.f};
        a = __builtin_amdgcn_mfma_f32_16x16x32_bf16(qf[t][0], kf0[ct], a, 0, 0, 0);
        a = __builtin_amdgcn_mfma_f32_16x16x32_bf16(qf[t][1], kf1[ct], a, 0, 0, 0);
        s[t][ct] = a;
      }
    }
    if (ch == 36) {
      s[0][3] = (f32x4){-1e30f, -1e30f, -1e30f, -1e30f};  // pad cols -> exp2=0
      s[1][3] = (f32x4){-1e30f, -1e30f, -1e30f, -1e30f};
    }
    // softmax numerator + PV, t-phases sequential through ONE per-wave P
    // buffer. Per-wave DS-op ordering: writes(t=1) cannot bypass reads(t=0).
    bf16* const Pw = Plds[wave];
#pragma unroll
    for (int t = 0; t < 2; ++t) {
      float csum[4] = {0.f, 0.f, 0.f, 0.f};
#pragma unroll
      for (int ct = 0; ct < 4; ++ct)
#pragma unroll
        for (int reg = 0; reg < 4; ++reg) {
          float p = exp2f(s[t][ct][reg]);
          s[t][ct][reg] = p;
          csum[reg] += p;
        }
#pragma unroll
      for (int reg = 0; reg < 4; ++reg)
        l[t][reg] += csum[reg];
#pragma unroll
      for (int ct = 0; ct < 4; ++ct)
#pragma unroll
        for (int reg = 0; reg < 4; ++reg)
          Pw[(q * 4 + reg) * 72 + ct * 16 + r] = (bf16)s[t][ct][reg];
      asm volatile("s_waitcnt lgkmcnt(0)" ::: "memory");
      __builtin_amdgcn_sched_barrier(0);
      const bf16x8 pf0 = *(const bf16x8*)&Pw[r * 72 + q * 8];
      const bf16x8 pf1 = *(const bf16x8*)&Pw[r * 72 + 32 + q * 8];
#pragma unroll
      for (int ot = 0; ot < 4; ++ot) {
        O[t][ot] = __builtin_amdgcn_mfma_f32_16x16x32_bf16(pf0, vf0[ot], O[t][ot], 0, 0, 0);
        O[t][ot] = __builtin_amdgcn_mfma_f32_16x16x32_bf16(pf1, vf1[ot], O[t][ot], 0, 0, 0);
      }
      __builtin_amdgcn_sched_barrier(0);
    }
  }
  // deferred cross-lane l reduction
#pragma unroll
  for (int t = 0; t < 2; ++t)
#pragma unroll
    for (int i = 0; i < 4; ++i) l[t][i] = rowsum16(l[t][i]);

  if (rt_raw < 74) {
#pragma unroll
    for (int t = 0; t < 2; ++t) {
      const int p = (z * 24 + inst) * 152 + rt * 2 + t;
      float* Op = Opart + (size_t)p * 1024;
#pragma unroll
      for (int ot = 0; ot < 4; ++ot)
#pragma unroll
        for (int reg = 0; reg < 4; ++reg)
          Op[(q * 4 + reg) * 64 + ot * 16 + r] = O[t][ot][reg];
      if (r == 0) {
#pragma unroll
        for (int reg = 0; reg < 4; ++reg)
          Lpart[(size_t)p * 16 + q * 4 + reg] = l[t][reg];
      }
    }
  }
}

// merge 3 split partials -> attnb bf16: (O1+O2+O3)/(l1+l2+l3)
__global__ __launch_bounds__(256) void attn_combine(
    const float* __restrict__ Opart, const float* __restrict__ Lpart,
    bf16* __restrict__ Og) {
  const int tile = blockIdx.x;   // 147
  const int inst = blockIdx.y;   // 24
  const int bb = inst / 12, hh = inst % 12;
  const int pb = inst * 152 + tile;
#pragma unroll
  for (int i = 0; i < 4; ++i) {
    const int e = threadIdx.x + 256 * i;   // 0..1023
    const int row = e >> 6, col = e & 63;
    const float lsum = Lpart[(size_t)pb * 16 + row] +
                       Lpart[(size_t)(3648 + pb) * 16 + row] +
                       Lpart[(size_t)(7296 + pb) * 16 + row];
    const float osum = Opart[(size_t)pb * 1024 + e] +
                       Opart[(size_t)(3648 + pb) * 1024 + e] +
                       Opart[(size_t)(7296 + pb) * 1024 + e];
    Og[(size_t)(bb * 2352 + tile * 16 + row) * 768 + hh * 64 + col] =
        (bf16)(osum / lsum);
  }
}

// --------------------------- small utility kernels -------------------------

__global__ void zero_pads(bf16* __restrict__ Q, bf16* __restrict__ Kb,
                          bf16* __restrict__ VT) {
  int i = blockIdx.x * 256 + threadIdx.x;
  if (i < 122880) {  // 24 inst * 80 rows * 64
    int inst = i / 5120, rem = i % 5120;
    Q[((size_t)inst * 2432 + 2352 + rem / 64) * 64 + (rem & 63)] = (bf16)0.f;
  }
  if (i < 24576) {   // 24 inst * 16 rows * 64
    int inst = i / 1024, rem = i % 1024;
    Kb[((size_t)inst * 2368 + 2352 + rem / 64) * 64 + (rem & 63)] = (bf16)0.f;
  }
  if (i < 24576) {   // 24 inst * 64 d * 16 s
    int inst = i / 1024, rem = i % 1024;
    VT[((size_t)inst * 64 + rem / 16) * 2368 + 2352 + (rem & 15)] = (bf16)0.f;
  }
}

__global__ void cvt_bf16(const float* __restrict__ x, bf16* __restrict__ y, int n) {
  int i = blockIdx.x * 256 + threadIdx.x;
  if (i < n) y[i] = (bf16)x[i];
}

__global__ void prep_pconv(const float* __restrict__ w, bf16* __restrict__ y) {
  int i = blockIdx.x * 256 + threadIdx.x;
  if (i >= 768 * 352) return;
  int d = i / 352, j = i % 352;
  y[i] = (bf16)(j < 343 ? w[d * 343 + j] : 0.f);
}

__global__ void im2col(const float* __restrict__ x, bf16* __restrict__ A) {
  int i = blockIdx.x * 256 + threadIdx.x;
  if (i >= 4704 * 352) return;
  int j = i % 352, tok = i / 352;
  float v = 0.f;
  if (j < 343) {
    int p = tok % 392, bt = tok / 392;
    int kx = j % 7, ky = (j / 7) % 7, kz = j / 49;
    int px = p % 7, py = (p / 7) % 7, pz = p / 49;
    int zz = pz * 7 + kz, yy = py * 7 + ky, xx = px * 7 + kx;
    v = x[(((size_t)bt * 56 + zz) * 49 + yy) * 49 + xx];
  }
  A[i] = (bf16)v;
}

template <typename OT>
__global__ __launch_bounds__(256) void ln_kernel(
    const float* __restrict__ x, const float* __restrict__ g,
    const float* __restrict__ bb, OT* __restrict__ y, int M) {
  int row = blockIdx.x * 4 + (threadIdx.x >> 6);
  int lane = threadIdx.x & 63;
  if (row >= M) return;
  const float* xr = x + (size_t)row * 768;
  float v[12], s = 0.f;
#pragma unroll
  for (int i = 0; i < 12; ++i) { v[i] = xr[lane + i * 64]; s += v[i]; }
#pragma unroll
  for (int off = 32; off; off >>= 1) s += __shfl_xor(s, off, 64);
  float mean = s * (1.f / 768.f);
  float vs = 0.f;
#pragma unroll
  for (int i = 0; i < 12; ++i) { float d = v[i] - mean; vs += d * d; }
#pragma unroll
  for (int off = 32; off; off >>= 1) vs += __shfl_xor(vs, off, 64);
  float inv = 1.f / sqrtf(vs * (1.f / 768.f) + 1e-6f);
#pragma unroll
  for (int i = 0; i < 12; ++i) {
    int j = lane + i * 64;
    y[(size_t)row * 768 + j] = (OT)((v[i] - mean) * inv * g[j] + bb[j]);
  }
}

__global__ __launch_bounds__(256) void dfc_kernel(
    const float* __restrict__ x, const float* __restrict__ w,
    const float* __restrict__ b0, float* __restrict__ z0, int M) {
  int row = blockIdx.x * 4 + (threadIdx.x >> 6);
  int lane = threadIdx.x & 63;
  if (row >= M) return;
  const float* xr = x + (size_t)row * 768;
  float s = 0.f;
#pragma unroll
  for (int i = 0; i < 12; ++i) s += xr[lane + i * 64] * w[lane + i * 64];
#pragma unroll
  for (int off = 32; off; off >>= 1) s += __shfl_xor(s, off, 64);
  if (lane == 0) z0[row] = s + b0[0];
}

__global__ void head_pe(const float* __restrict__ z0, float* __restrict__ z1) {
  int i = blockIdx.x * 256 + threadIdx.x;
  if (i >= 784) return;
  int b = i / 392, p = i % 392;
  float vals[6], m = 0.f;
#pragma unroll
  for (int t = 0; t < 6; ++t) { vals[t] = z0[(b * 6 + t) * 392 + p]; m += vals[t]; }
  m *= (1.f / 6.f);
  float e = (float)(2 * (p >> 1)) / 392.0f;
  float div = powf(10000.f, -e);
#pragma unroll
  for (int t = 0; t < 6; ++t) {
    float arg = (float)t * div;
    float pe = (p & 1) ? cosf(arg) : sinf(arg);
    z1[(b * 6 + t) * 392 + p] = vals[t] - m + pe;
  }
}

// ---- decoder-head convs ---------------------------------------------------
template <int ID, int IH, int IW, int PD, int PH, int PWA, int OFF, int ST>
__global__ void pad_in(const float* __restrict__ x, float* __restrict__ Xp) {
  int i = blockIdx.x * 256 + threadIdx.x;
  constexpr int total = 12 * PD * PH * PWA;
  if (i >= total) return;
  int px = i % PWA, t1 = i / PWA;
  int py = t1 % PH, t2 = t1 / PH;
  int pz = t2 % PD, c = t2 / PD;
  float v = 0.f;
  int tz = pz - OFF, ty = py - OFF, tx = px - OFF;
  if (tz >= 0 && ty >= 0 && tx >= 0 &&
      (ST == 1 || (((tz | ty | tx) & 1) == 0))) {
    int iz = tz / ST, iy = ty / ST, ix = tx / ST;
    if (iz < ID && iy < IH && ix < IW)
      v = x[((size_t)(c * ID + iz) * IH + iy) * IW + ix];
  }
  Xp[i] = v;
}

template <int PD, int PH, int PWA, int OD, int OH, int OW, int K, int DIL>
__global__ __launch_bounds__(256) void convt4(
    const float* __restrict__ Xp, const float* __restrict__ w,
    const float* __restrict__ bias, float* __restrict__ y) {
  constexpr int P0  = (K - 1) * DIL;
  constexpr int QX  = (OW + 3) / 4;
  constexpr int NLD = (P0 + 4 + 3) / 4;
  int idx = blockIdx.x * 256 + threadIdx.x;
  if (idx >= OD * OH * QX) return;
  int c = blockIdx.y;
  int qx = idx % QX; int t1 = idx / QX;
  int oy = t1 % OH;  int oz = t1 / OH;
  int ox0 = qx * 4;
  const float* xc = Xp + (size_t)c * (PD * PH * PWA);
  const float* wc = w + (c % 6) * (K * K * K);
  const float bv = bias[c % 6];
  float a0 = bv, a1 = bv, a2 = bv, a3 = bv;
  for (int kz = 0; kz < K; ++kz) {
    const int bz = oz + P0 - kz * DIL;
#pragma unroll
    for (int ky = 0; ky < K; ++ky) {
      const int by = oy + P0 - ky * DIL;
      const float* base = xc + ((size_t)bz * PH + by) * PWA + ox0;
      float buf[NLD * 4];
#pragma unroll
      for (int i = 0; i < NLD; ++i)
        *(f32x4*)&buf[i * 4] = *(const f32x4*)(base + i * 4);
      const float* wr = wc + (kz * K + ky) * K;
#pragma unroll
      for (int kx = 0; kx < K; ++kx) {
        const float wv = wr[kx];
        const int j = P0 - kx * DIL;
        a0 += wv * buf[j + 0];
        a1 += wv * buf[j + 1];
        a2 += wv * buf[j + 2];
        a3 += wv * buf[j + 3];
      }
    }
  }
  float* yp = y + (size_t)c * (OD * OH * OW) + ((size_t)oz * OH + oy) * OW + ox0;
  yp[0] = a0;
  if (ox0 + 1 < OW) yp[1] = a1;
  if (ox0 + 2 < OW) yp[2] = a2;
  if (ox0 + 3 < OW) yp[3] = a3;
}

__global__ void head_final(const float* __restrict__ z4, const float* __restrict__ hw,
                           const float* __restrict__ hb, float* __restrict__ out) {
  int idx = blockIdx.x * 256 + threadIdx.x;
  if (idx >= 1613472) return;
  int t = idx % 6, rdx = idx / 6;
  int xx = rdx % 49; rdx /= 49;
  int yy = rdx % 49; rdx /= 49;
  int zz = rdx % 56; int b = rdx / 56;
  const float rz = (float)(47.0 / 56.0), ry = (float)(45.0 / 49.0);
  int iz = (int)((float)zz * rz);
  int iy = (int)((float)yy * ry);
  int ix = (int)((float)xx * ry);
  float v = z4[(((size_t)(b * 6 + t) * 47 + iz) * 45 + iy) * 45 + ix];
  v = v * hw[t] + hb[t];
  v = (v >= 0.f) ? v : (11.0f / 48.0f) * v;
  out[idx] = v;
}

// ---------------------------------------------------------------------------

static inline void launch_gemm(hipStream_t s, const bf16* A, const bf16* B,
                               float* Cf, bf16* Cb, const float* bias,
                               const float* addp, int addmod, int rrelu,
                               int M, int N, int K, int lda, int ldb, int ldc,
                               long long sA, long long sB, long long sC,
                               int nz, int ksplit = 1,
                               bf16* Qo = nullptr, bf16* Ko = nullptr,
                               bf16* Vo = nullptr) {
  dim3 g(CDIV(M, 128), CDIV(N, 64), ksplit > 1 ? ksplit : nz);
  gemm_bt<<<g, 256, 0, s>>>(A, B, Cf, Cb, bias, addp, addmod, rrelu,
                            M, N, K, lda, ldb, ldc, sA, sB, sC, ksplit,
                            Qo, Ko, Vo);
}

extern "C" void kernel_launch(void* const* d_in, const int* in_sizes, int n_in,
                              void* d_out, int out_size, void* d_ws, size_t ws_size,
                              hipStream_t stream) {
  (void)in_sizes; (void)n_in; (void)out_size; (void)ws_size;
  const float* x       = (const float*)d_in[0];
  const float* pconv_w = (const float*)d_in[1];
  const float* pconv_b = (const float*)d_in[2];
  const float* pos_emb = (const float*)d_in[3];
  const float* ln1_g   = (const float*)d_in[4];
  const float* ln1_b   = (const float*)d_in[5];
  const float* qkv_wf  = (const float*)d_in[6];
  const float* qkv_b   = (const float*)d_in[7];
  const float* proj_wf = (const float*)d_in[8];
  const float* proj_b  = (const float*)d_in[9];
  const float* ln2_g   = (const float*)d_in[10];
  const float* ln2_b   = (const float*)d_in[11];
  const float* fc1_wf  = (const float*)d_in[12];
  const float* fc1_b   = (const float*)d_in[13];
  const float* fc2_wf  = (const float*)d_in[14];
  const float* fc2_b   = (const float*)d_in[15];
  const float* normf_g = (const float*)d_in[16];
  const float* normf_b = (const float*)d_in[17];
  const float* dfc_w   = (const float*)d_in[18];
  const float* dfc_b   = (const float*)d_in[19];
  const float* up1_w   = (const float*)d_in[20];
  const float* up1_b   = (const float*)d_in[21];
  const float* up2_w   = (const float*)d_in[22];
  const float* up2_b   = (const float*)d_in[23];
  const float* up3_w   = (const float*)d_in[24];
  const float* up3_b   = (const float*)d_in[25];
  const float* hconv_w = (const float*)d_in[26];
  const float* hconv_b = (const float*)d_in[27];
  float* out = (float*)d_out;

  char* ws = (char*)d_ws;
  size_t off = 0;
  auto alloc = [&](size_t bytes) -> void* {
    void* p = ws + off;
    off += (bytes + 255) & ~(size_t)255;
    return p;
  };
  float* tok   = (float*)alloc(4704UL * 768 * 4);
  bf16* lnout  = (bf16*)alloc(4704UL * 768 * 2);
  bf16* Qb     = (bf16*)alloc(24UL * 2432 * 64 * 2);
  bf16* Kb     = (bf16*)alloc(24UL * 2368 * 64 * 2);
  bf16* VT     = (bf16*)alloc(24UL * 64 * 2368 * 2);
  bf16* attnb  = (bf16*)alloc(4704UL * 768 * 2);
  bf16* hb     = (bf16*)alloc(4704UL * 3072 * 2);
  bf16* Apatch = (bf16*)alloc(4704UL * 352 * 2);
  bf16* Wq     = (bf16*)alloc(2UL * 2304 * 768 * 2);
  bf16* Wp     = (bf16*)alloc(2UL * 768 * 768 * 2);
  bf16* W1     = (bf16*)alloc(2UL * 3072 * 768 * 2);
  bf16* W2     = (bf16*)alloc(2UL * 768 * 3072 * 2);
  bf16* Wpc    = (bf16*)alloc(768UL * 352 * 2);
  float* Opart = (float*)alloc(3UL * 24 * 152 * 1024 * 4);   // 44.8 MB
  float* Lpart = (float*)alloc(3UL * 24 * 152 * 16 * 4);
  float* z0    = (float*)alloc(4704UL * 4);
  float* z1    = (float*)alloc(4704UL * 4);
  float* z2    = (float*)alloc(12UL * 14 * 13 * 13 * 4);
  float* z3    = (float*)alloc(12UL * 31 * 29 * 29 * 4);
  float* z4    = (float*)alloc(12UL * 47 * 45 * 45 * 4);
  float* p1    = (float*)alloc(12UL * 20 * 19 * 24 * 4);
  float* p2    = (float*)alloc(12UL * 35 * 33 * 36 * 4);
  float* p3    = (float*)alloc(12UL * 63 * 61 * 64 * 4);
  float* lnf   = (float*)alloc(4704UL * 768 * 4);

  // ---- weight prep (bf16) + pad zeroing ----
  cvt_bf16<<<CDIV(3538944, 256), 256, 0, stream>>>(qkv_wf, Wq, 3538944);
  cvt_bf16<<<CDIV(1179648, 256), 256, 0, stream>>>(proj_wf, Wp, 1179648);
  cvt_bf16<<<CDIV(4718592, 256), 256, 0, stream>>>(fc1_wf, W1, 4718592);
  cvt_bf16<<<CDIV(4718592, 256), 256, 0, stream>>>(fc2_wf, W2, 4718592);
  prep_pconv<<<CDIV(768 * 352, 256), 256, 0, stream>>>(pconv_w, Wpc);
  zero_pads<<<CDIV(122880, 256), 256, 0, stream>>>(Qb, Kb, VT);

  // ---- patch embed (as GEMM) + bias + pos_embed -> tok (fp32) ----
  im2col<<<CDIV(4704 * 352, 256), 256, 0, stream>>>(x, Apatch);
  launch_gemm(stream, Apatch, Wpc, tok, nullptr, pconv_b, pos_emb, 2352, 0,
              4704, 768, 352, 352, 352, 768, 0, 0, 0, 1);

  // ---- transformer layers ----
  for (int i = 0; i < 2; ++i) {
    ln_kernel<bf16><<<1176, 256, 0, stream>>>(tok, ln1_g + i * 768, ln1_b + i * 768, lnout, 4704);
    launch_gemm(stream, lnout, Wq + (size_t)i * 2304 * 768, nullptr, nullptr,
                qkv_b + i * 2304, nullptr, 1, 0,
                4704, 2304, 768, 768, 768, 2304, 0, 0, 0, 1, 1, Qb, Kb, VT);
    flash_attn_split<<<dim3(19, 24, 3), 256, 0, stream>>>(Qb, Kb, VT, Opart, Lpart);
    attn_combine<<<dim3(147, 24), 256, 0, stream>>>(Opart, Lpart, attnb);
    launch_gemm(stream, attnb, Wp + (size_t)i * 768 * 768, tok, nullptr,
                proj_b + i * 768, nullptr, 1, 0,
                4704, 768, 768, 768, 768, 768, 0, 0, 0, 1, 4);
    ln_kernel<bf16><<<1176, 256, 0, stream>>>(tok, ln2_g + i * 768, ln2_b + i * 768, lnout, 4704);
    launch_gemm(stream, lnout, W1 + (size_t)i * 3072 * 768, nullptr, hb,
                fc1_b + i * 3072, nullptr, 1, 1,
                4704, 3072, 768, 768, 768, 3072, 0, 0, 0, 1);
    launch_gemm(stream, hb, W2 + (size_t)i * 768 * 3072, tok, nullptr,
                fc2_b + i * 768, nullptr, 1, 0,
                4704, 768, 3072, 3072, 3072, 768, 0, 0, 0, 1, 4);
  }

  // ---- decoder head (fp32) ----
  ln_kernel<float><<<1176, 256, 0, stream>>>(tok, normf_g, normf_b, lnf, 4704);
  dfc_kernel<<<1176, 256, 0, stream>>>(lnf, dfc_w, dfc_b, z0, 4704);
  head_pe<<<4, 256, 0, stream>>>(z0, z1);

  pad_in<8, 7, 7, 20, 19, 24, 6, 1>
      <<<CDIV(12 * 20 * 19 * 24, 256), 256, 0, stream>>>(z1, p1);
  convt4<20, 19, 24, 14, 13, 13, 7, 1>
      <<<dim3(CDIV(14 * 13 * 4, 256), 12), 256, 0, stream>>>(p1, up1_w, up1_b, z2);
  pad_in<14, 13, 13, 35, 33, 36, 4, 2>
      <<<CDIV(12 * 35 * 33 * 36, 256), 256, 0, stream>>>(z2, p2);
  convt4<35, 33, 36, 31, 29, 29, 5, 1>
      <<<dim3(CDIV(31 * 29 * 8, 256), 12), 256, 0, stream>>>(p2, up2_w, up2_b, z3);
  pad_in<31, 29, 29, 63, 61, 64, 16, 1>
      <<<CDIV(12 * 63 * 61 * 64, 256), 256, 0, stream>>>(z3, p3);
  convt4<63, 61, 64, 47, 45, 45, 9, 2>
      <<<dim3(CDIV(47 * 45 * 12, 256), 12), 256, 0, stream>>>(p3, up3_w, up3_b, z4);

  head_final<<<CDIV(1613472, 256), 256, 0, stream>>>(z4, hconv_w, hconv_b, out);
}

// Round 11
// 1011.212 us; speedup vs baseline: 1.0182x; 1.0182x over previous
//
#include <hip/hip_runtime.h>

// ---------------------------------------------------------------------------
// ScepterVisionTransformer forward on MI355X (gfx950).
// R21:
//  * flash_attn: reverted to R19 config (ksplit=2, dual per-t Plds buffers;
//    measured 88.5us). R20's split-3 + single-Plds added 15MB HBM write
//    traffic with zero occupancy gain (derived OccupancyPercent is
//    unreliable on gfx950 — R19 was already fully co-resident by LDS
//    arithmetic) -> +3.4us/dispatch regression.
//  * cvt_bf16 vectorized 8x (f32x4 x2 -> bf16x8): weight prep was scalar
//    2B stores (Common-mistake #2), ~2x slower than needed on 14.2M elems.
//  * gemm_bt: unchanged (128x64 tile, reg-staged pipeline, XCD swizzle).
// ---------------------------------------------------------------------------

#define AS1 __attribute__((address_space(1)))
#define AS3 __attribute__((address_space(3)))

using bf16 = __bf16;
typedef __bf16 bf16x8 __attribute__((ext_vector_type(8)));
typedef float  f32x4  __attribute__((ext_vector_type(4)));

#define CDIV(a, b) (((a) + (b) - 1) / (b))

// DPP row_ror within 16-lane row
template <int SH>
__device__ __forceinline__ float rorf(float x) {
  int i = __builtin_amdgcn_update_dpp(0, __builtin_bit_cast(int, x),
                                      0x120 + SH, 0xF, 0xF, false);
  return __builtin_bit_cast(float, i);
}
__device__ __forceinline__ float rowsum16(float v) {
  v += rorf<1>(v); v += rorf<2>(v); v += rorf<4>(v); v += rorf<8>(v);
  return v;
}

// ---------------------------------------------------------------------------
// Generic GEMM: C(MxN) = A(MxK) * B^T (B stored N-major), bf16 in, fp32 acc.
// Tile 128x64, 4 waves (2M x 2N, each 64x32 out). Reg-staged pipeline:
// tile t+1 in VGPRs, compute t, then write t+1 to the alternate LDS buffer
// and issue loads for t+2. One raw barrier per K-step.
// ksplit>1: partials atomicAdd'ed into Cf (residual-carrying), bias on z==0.
// Qo!=null: qkv-repack epilogue — writes Q/K(scaled)/VT bf16 directly.
// ---------------------------------------------------------------------------
__global__ __launch_bounds__(256) void gemm_bt(
    const bf16* __restrict__ A, const bf16* __restrict__ B,
    float* Cf, bf16* Cb, const float* __restrict__ bias,
    const float* addp, int addmod, int rrelu,
    int M, int N, int K, int lda, int ldb, int ldc,
    long long sA, long long sB, long long sC, int ksplit,
    bf16* __restrict__ Qo, bf16* __restrict__ Ko, bf16* __restrict__ Vo) {
  __shared__ __align__(16) bf16 As[2][128 * 32];   // 8KB x2
  __shared__ __align__(16) bf16 Bs[2][64 * 32];    // 4KB x2  => 24KB total
  const int tid  = threadIdx.x;
  const int lane = tid & 63;
  const int wave = tid >> 6;
  const int wm = wave & 1;
  const int wn = wave >> 1;
  const int q  = lane >> 4;
  const int r  = lane & 15;

  // bijective XCD-aware swizzle of the flat tile index (m204 formula)
  const int nwg = gridDim.x * gridDim.y;
  int flat = blockIdx.y * gridDim.x + blockIdx.x;
  {
    const int qq = nwg >> 3, rr = nwg & 7;
    const int xcd = flat & 7, lid = flat >> 3;
    flat = (xcd < rr ? xcd * (qq + 1) : rr * (qq + 1) + (xcd - rr) * qq) + lid;
  }
  const int tm0 = (flat % gridDim.x) * 128;
  const int tn0 = (flat / gridDim.x) * 64;
  const int z   = blockIdx.z;

  const bf16* Ab = A + (ksplit > 1 ? 0 : (size_t)z * (size_t)sA);
  const bf16* Bb = B + (ksplit > 1 ? 0 : (size_t)z * (size_t)sB);
  int kb = 0, ke = K;
  if (ksplit > 1) {
    const int kc = ((K / ksplit + 31) / 32) * 32;
    kb = z * kc;
    ke = min(kb + kc, K);
  }
  const int nt = (ke - kb + 31) >> 5;

  const int arow0 = min(tm0 + (tid >> 2), M - 1);
  const int arow1 = min(tm0 + (tid >> 2) + 64, M - 1);
  const int brow0 = min(tn0 + (tid >> 2), N - 1);
  const int kcol  = (tid & 3) * 8;
  const bf16* ap0 = Ab + (size_t)arow0 * lda + kcol;
  const bf16* ap1 = Ab + (size_t)arow1 * lda + kcol;
  const bf16* bp0 = Bb + (size_t)brow0 * ldb + kcol;

  f32x4 acc[4][2];
#pragma unroll
  for (int mi = 0; mi < 4; ++mi)
#pragma unroll
    for (int ni = 0; ni < 2; ++ni) acc[mi][ni] = (f32x4){0.f, 0.f, 0.f, 0.f};

  // staged tile registers (one K-step: A 2x16B + B 1x16B per thread)
  bf16x8 rA0, rA1, rB0;
  auto loadT = [&](int t) {
    const int k0 = kb + (t << 5);
    rA0 = *(const bf16x8*)(ap0 + k0);
    rA1 = *(const bf16x8*)(ap1 + k0);
    rB0 = *(const bf16x8*)(bp0 + k0);
  };
  // LDS row-major [rows][32]; thread tid owns elems [tid*8, tid*8+8).
  auto writeT = [&](int buf) {
    *(bf16x8*)&As[buf][tid * 8]        = rA0;
    *(bf16x8*)&As[buf][2048 + tid * 8] = rA1;
    *(bf16x8*)&Bs[buf][tid * 8]        = rB0;
  };

  // prologue: tile 0 -> LDS[0] (exposed once), tile 1 -> regs
  loadT(0);
  writeT(0);
  if (nt > 1) loadT(1);

  for (int t = 0; t < nt; ++t) {
    const int cur = t & 1;
    // own ds ops drained, then block-wide barrier: LDS[cur] (written last
    // iter) visible; all waves done reading LDS[cur^1].
    asm volatile("s_waitcnt lgkmcnt(0)" ::: "memory");
    __builtin_amdgcn_sched_barrier(0);
    __builtin_amdgcn_s_barrier();
    asm volatile("" ::: "memory");
    bf16x8 af[4], bfr[2];
#pragma unroll
    for (int mi = 0; mi < 4; ++mi)
      af[mi] = *(const bf16x8*)&As[cur][(wm * 64 + mi * 16 + r) * 32 + q * 8];
#pragma unroll
    for (int ni = 0; ni < 2; ++ni)
      bfr[ni] = *(const bf16x8*)&Bs[cur][(wn * 32 + ni * 16 + r) * 32 + q * 8];
#pragma unroll
    for (int mi = 0; mi < 4; ++mi)
#pragma unroll
      for (int ni = 0; ni < 2; ++ni)
        acc[mi][ni] = __builtin_amdgcn_mfma_f32_16x16x32_bf16(
            af[mi], bfr[ni], acc[mi][ni], 0, 0, 0);
    // staging BELOW the MFMAs (compute-early/write-late)
    __builtin_amdgcn_sched_barrier(0);
    if (t + 1 < nt) {
      writeT(cur ^ 1);
      if (t + 2 < nt) loadT(t + 2);
    }
  }

  float* cf = Cf ? Cf + (ksplit > 1 ? 0 : (size_t)z * (size_t)sC) : nullptr;
  bf16*  cb = Cb ? Cb + (ksplit > 1 ? 0 : (size_t)z * (size_t)sC) : nullptr;
#pragma unroll
  for (int mi = 0; mi < 4; ++mi) {
    const int row0 = tm0 + wm * 64 + mi * 16 + q * 4;
#pragma unroll
    for (int ni = 0; ni < 2; ++ni) {
      const int col = tn0 + wn * 32 + ni * 16 + r;
      if (col >= N) continue;
      const float bv = bias ? bias[col] : 0.f;
#pragma unroll
      for (int reg = 0; reg < 4; ++reg) {
        const int rr = row0 + reg;
        if (rr >= M) continue;
        if (Qo) {
          const float v = acc[mi][ni][reg] + bv;
          const int which = col / 768;
          const int hh = (col % 768) >> 6;
          const int dd = col & 63;
          const int bb2 = rr / 2352;
          const int ss = rr - bb2 * 2352;
          const int inst = bb2 * 12 + hh;
          if (which == 0)
            Qo[((size_t)inst * 2432 + ss) * 64 + dd] = (bf16)v;
          else if (which == 1)
            Ko[((size_t)inst * 2368 + ss) * 64 + dd] = (bf16)(v * 0.18033688f);
          else
            Vo[((size_t)inst * 64 + dd) * 2368 + ss] = (bf16)v;
        } else if (ksplit > 1) {
          float v = acc[mi][ni][reg];
          if (z == 0) {
            v += bv;
            if (addp) v += addp[(size_t)(rr % addmod) * ldc + col];
          }
          atomicAdd(&cf[(size_t)rr * ldc + col], v);
        } else {
          float v = acc[mi][ni][reg] + bv;
          if (addp) v += addp[(size_t)(rr % addmod) * ldc + col];
          if (rrelu) v = (v >= 0.f) ? v : 0.4f * v;
          if (cf) cf[(size_t)rr * ldc + col] = v;
          else    cb[(size_t)rr * ldc + col] = (bf16)v;
        }
      }
    }
  }
}

// ---------------------------------------------------------------------------
// Flash attention (R19 config): one wave = 32 Q-rows; 2 K-splits. Next
// chunk's K/V loaded into REGISTERS during current chunk's compute (T14);
// per-lane swizzled ds_write_b128 into single-buffered LDS; dual per-t
// Plds buffers. Raw s_barrier + lgkmcnt(0) fences; vmcnt never drained;
// l-reduction deferred out of the loop. LDS 34.8KB -> 4 blocks/CU, full
// 912-block grid co-resident.
// ---------------------------------------------------------------------------
__global__ __launch_bounds__(256) void flash_attn_split(
    const bf16* __restrict__ Qg, const bf16* __restrict__ Kg,
    const bf16* __restrict__ Vt, float* __restrict__ Opart,
    float* __restrict__ Lpart) {
  __shared__ __align__(16) bf16 Kl[64 * 64];   // 8KB, swizzled
  __shared__ __align__(16) bf16 Vl[64 * 64];   // 8KB, swizzled (rows = d)
  __shared__ __align__(16) bf16 Plds[4][2][16 * 72];
  const int tid  = threadIdx.x;
  const int lane = tid & 63;
  const int wave = tid >> 6;
  const int q = lane >> 4, r = lane & 15;
  const int inst = blockIdx.y;
  const int z = blockIdx.z;
  const int rt_raw = blockIdx.x * 4 + wave;   // 0..75
  const int rt = min(rt_raw, 73);             // clamp: redundant compute, all
                                              // waves participate in barriers
  const int row0 = rt * 32;
  const int ch0 = (z * 37) >> 1;              // 0, 18
  const int ch1 = ((z + 1) * 37) >> 1;        // 18, 37
  const bf16* Qi = Qg + (size_t)inst * 2432 * 64;
  const bf16* Ki = Kg + (size_t)inst * 2368 * 64;
  const bf16* Vi = Vt + (size_t)inst * 64 * 2368;

  bf16x8 qf[2][2];
#pragma unroll
  for (int t = 0; t < 2; ++t) {
    qf[t][0] = *(const bf16x8*)&Qi[(size_t)(row0 + t * 16 + r) * 64 + q * 8];
    qf[t][1] = *(const bf16x8*)&Qi[(size_t)(row0 + t * 16 + r) * 64 + 32 + q * 8];
  }

  f32x4 O[2][4];
  float l[2][4];
#pragma unroll
  for (int t = 0; t < 2; ++t)
#pragma unroll
    for (int i = 0; i < 4; ++i) {
      O[t][i] = (f32x4){0.f, 0.f, 0.f, 0.f};
      l[t][i] = 0.f;
    }

  // ---- T14 reg-staging layout: thread -> (row srow, 16B-unit suc) and
  // (srow+32, suc); global src pre-swizzled so LDS stays linear.
  const int srow = tid >> 3;                 // 0..31
  const int suc  = tid & 7;                  // 0..7
  const int gu   = (suc ^ (srow & 7)) * 8;   // swizzled global unit (elems)
  bf16* const kd0 = &Kl[srow * 64 + suc * 8];
  bf16* const kd1 = &Kl[(srow + 32) * 64 + suc * 8];
  bf16* const vd0 = &Vl[srow * 64 + suc * 8];
  bf16* const vd1 = &Vl[(srow + 32) * 64 + suc * 8];
  const int swz = (r & 7);   // frag-read swizzle key (row & 7 == r & 7)

  bf16x8 kr0, kr1, vr0, vr1;
  auto loadKV = [&](int ch) {
    const size_t col0 = (size_t)ch * 64;
    kr0 = *(const bf16x8*)&Ki[(col0 + srow) * 64 + gu];
    kr1 = *(const bf16x8*)&Ki[(col0 + srow + 32) * 64 + gu];
    vr0 = *(const bf16x8*)&Vi[(size_t)srow * 2368 + col0 + gu];
    vr1 = *(const bf16x8*)&Vi[(size_t)(srow + 32) * 2368 + col0 + gu];
  };

  loadKV(ch0);   // prologue: chunk ch0 in flight
  for (int ch = ch0; ch < ch1; ++ch) {
    // barrier A: all waves done reading LDS for the previous chunk.
    asm volatile("s_waitcnt lgkmcnt(0)" ::: "memory");
    __builtin_amdgcn_sched_barrier(0);
    __builtin_amdgcn_s_barrier();
    asm volatile("" ::: "memory");
    // write staged regs -> LDS (compiler inserts vmcnt waits for reg deps;
    // those loads had a full compute phase to land)
    *(bf16x8*)kd0 = kr0;
    *(bf16x8*)kd1 = kr1;
    *(bf16x8*)vd0 = vr0;
    *(bf16x8*)vd1 = vr1;
    if (ch + 1 < ch1) loadKV(ch + 1);   // issue next chunk, stays in flight
    asm volatile("s_waitcnt lgkmcnt(0)" ::: "memory");
    __builtin_amdgcn_sched_barrier(0);
    // barrier B: all waves' ds_writes visible; vmcnt NOT drained
    __builtin_amdgcn_s_barrier();
    asm volatile("" ::: "memory");

    // frag reads from LDS (swizzled, conflict-free)
    bf16x8 kf0[4], kf1[4], vf0[4], vf1[4];
#pragma unroll
    for (int ct = 0; ct < 4; ++ct) {
      const int krow = ct * 16 + r;
      kf0[ct] = *(const bf16x8*)&Kl[krow * 64 + ((q ^ swz) * 8)];
      kf1[ct] = *(const bf16x8*)&Kl[krow * 64 + (((q + 4) ^ swz) * 8)];
      vf0[ct] = *(const bf16x8*)&Vl[krow * 64 + ((q ^ swz) * 8)];
      vf1[ct] = *(const bf16x8*)&Vl[krow * 64 + (((q + 4) ^ swz) * 8)];
    }

    // S = QK' (scale folded into K), both tiles
    f32x4 s[2][4];
#pragma unroll
    for (int ct = 0; ct < 4; ++ct) {
#pragma unroll
      for (int t = 0; t < 2; ++t) {
        f32x4 a = (f32x4){0.f, 0.f, 0.f, 0.f};
        a = __builtin_amdgcn_mfma_f32_16x16x32_bf16(qf[t][0], kf0[ct], a, 0, 0, 0);
        a = __builtin_amdgcn_mfma_f32_16x16x32_bf16(qf[t][1], kf1[ct], a, 0, 0, 0);
        s[t][ct] = a;
      }
    }
    if (ch == 36) {
      s[0][3] = (f32x4){-1e30f, -1e30f, -1e30f, -1e30f};  // pad cols -> exp2=0
      s[1][3] = (f32x4){-1e30f, -1e30f, -1e30f, -1e30f};
    }
    // softmax numerator: P = exp2(S), no max-shift (scores bounded).
    // l kept as PER-LANE partial; cross-lane rowsum16 deferred to epilogue.
#pragma unroll
    for (int t = 0; t < 2; ++t) {
      float csum[4] = {0.f, 0.f, 0.f, 0.f};
#pragma unroll
      for (int ct = 0; ct < 4; ++ct)
#pragma unroll
        for (int reg = 0; reg < 4; ++reg) {
          float p = exp2f(s[t][ct][reg]);
          s[t][ct][reg] = p;
          csum[reg] += p;
        }
#pragma unroll
      for (int reg = 0; reg < 4; ++reg)
        l[t][reg] += csum[reg];
      bf16* Pw = Plds[wave][t];
#pragma unroll
      for (int ct = 0; ct < 4; ++ct)
#pragma unroll
        for (int reg = 0; reg < 4; ++reg)
          Pw[(q * 4 + reg) * 72 + ct * 16 + r] = (bf16)s[t][ct][reg];
    }
#pragma unroll
    for (int t = 0; t < 2; ++t) {
      const bf16* Pw = Plds[wave][t];
      const bf16x8 pf0 = *(const bf16x8*)&Pw[r * 72 + q * 8];
      const bf16x8 pf1 = *(const bf16x8*)&Pw[r * 72 + 32 + q * 8];
#pragma unroll
      for (int ot = 0; ot < 4; ++ot) {
        O[t][ot] = __builtin_amdgcn_mfma_f32_16x16x32_bf16(pf0, vf0[ot], O[t][ot], 0, 0, 0);
        O[t][ot] = __builtin_amdgcn_mfma_f32_16x16x32_bf16(pf1, vf1[ot], O[t][ot], 0, 0, 0);
      }
    }
  }
  // deferred cross-lane l reduction (8 rowsum16 total, was 8/chunk)
#pragma unroll
  for (int t = 0; t < 2; ++t)
#pragma unroll
    for (int i = 0; i < 4; ++i) l[t][i] = rowsum16(l[t][i]);

  if (rt_raw < 74) {
#pragma unroll
    for (int t = 0; t < 2; ++t) {
      const int p = (z * 24 + inst) * 152 + rt * 2 + t;
      float* Op = Opart + (size_t)p * 1024;
#pragma unroll
      for (int ot = 0; ot < 4; ++ot)
#pragma unroll
        for (int reg = 0; reg < 4; ++reg)
          Op[(q * 4 + reg) * 64 + ot * 16 + r] = O[t][ot][reg];
      if (r == 0) {
#pragma unroll
        for (int reg = 0; reg < 4; ++reg)
          Lpart[(size_t)p * 16 + q * 4 + reg] = l[t][reg];
      }
    }
  }
}

// merge 2 split partials -> attnb bf16: (O1+O2)/(l1+l2)
__global__ __launch_bounds__(256) void attn_combine(
    const float* __restrict__ Opart, const float* __restrict__ Lpart,
    bf16* __restrict__ Og) {
  const int tile = blockIdx.x;   // 147
  const int inst = blockIdx.y;   // 24
  const int bb = inst / 12, hh = inst % 12;
  const int pb = inst * 152 + tile;
#pragma unroll
  for (int i = 0; i < 4; ++i) {
    const int e = threadIdx.x + 256 * i;   // 0..1023
    const int row = e >> 6, col = e & 63;
    const float lsum = Lpart[(size_t)pb * 16 + row] +
                       Lpart[(size_t)(3648 + pb) * 16 + row];
    const float osum = Opart[(size_t)pb * 1024 + e] +
                       Opart[(size_t)(3648 + pb) * 1024 + e];
    Og[(size_t)(bb * 2352 + tile * 16 + row) * 768 + hh * 64 + col] =
        (bf16)(osum / lsum);
  }
}

// --------------------------- small utility kernels -------------------------

__global__ void zero_pads(bf16* __restrict__ Q, bf16* __restrict__ Kb,
                          bf16* __restrict__ VT) {
  int i = blockIdx.x * 256 + threadIdx.x;
  if (i < 122880) {  // 24 inst * 80 rows * 64
    int inst = i / 5120, rem = i % 5120;
    Q[((size_t)inst * 2432 + 2352 + rem / 64) * 64 + (rem & 63)] = (bf16)0.f;
  }
  if (i < 24576) {   // 24 inst * 16 rows * 64
    int inst = i / 1024, rem = i % 1024;
    Kb[((size_t)inst * 2368 + 2352 + rem / 64) * 64 + (rem & 63)] = (bf16)0.f;
  }
  if (i < 24576) {   // 24 inst * 64 d * 16 s
    int inst = i / 1024, rem = i % 1024;
    VT[((size_t)inst * 64 + rem / 16) * 2368 + 2352 + (rem & 15)] = (bf16)0.f;
  }
}

// vectorized fp32 -> bf16 (8 elems/thread); n must be a multiple of 8
__global__ void cvt_bf16(const float* __restrict__ x, bf16* __restrict__ y, int n) {
  int i = (blockIdx.x * 256 + threadIdx.x) * 8;
  if (i >= n) return;
  f32x4 a = *(const f32x4*)(x + i);
  f32x4 b = *(const f32x4*)(x + i + 4);
  bf16x8 o;
  o[0] = (bf16)a[0]; o[1] = (bf16)a[1]; o[2] = (bf16)a[2]; o[3] = (bf16)a[3];
  o[4] = (bf16)b[0]; o[5] = (bf16)b[1]; o[6] = (bf16)b[2]; o[7] = (bf16)b[3];
  *(bf16x8*)(y + i) = o;
}

__global__ void prep_pconv(const float* __restrict__ w, bf16* __restrict__ y) {
  int i = blockIdx.x * 256 + threadIdx.x;
  if (i >= 768 * 352) return;
  int d = i / 352, j = i % 352;
  y[i] = (bf16)(j < 343 ? w[d * 343 + j] : 0.f);
}

__global__ void im2col(const float* __restrict__ x, bf16* __restrict__ A) {
  int i = blockIdx.x * 256 + threadIdx.x;
  if (i >= 4704 * 352) return;
  int j = i % 352, tok = i / 352;
  float v = 0.f;
  if (j < 343) {
    int p = tok % 392, bt = tok / 392;
    int kx = j % 7, ky = (j / 7) % 7, kz = j / 49;
    int px = p % 7, py = (p / 7) % 7, pz = p / 49;
    int zz = pz * 7 + kz, yy = py * 7 + ky, xx = px * 7 + kx;
    v = x[(((size_t)bt * 56 + zz) * 49 + yy) * 49 + xx];
  }
  A[i] = (bf16)v;
}

template <typename OT>
__global__ __launch_bounds__(256) void ln_kernel(
    const float* __restrict__ x, const float* __restrict__ g,
    const float* __restrict__ bb, OT* __restrict__ y, int M) {
  int row = blockIdx.x * 4 + (threadIdx.x >> 6);
  int lane = threadIdx.x & 63;
  if (row >= M) return;
  const float* xr = x + (size_t)row * 768;
  float v[12], s = 0.f;
#pragma unroll
  for (int i = 0; i < 12; ++i) { v[i] = xr[lane + i * 64]; s += v[i]; }
#pragma unroll
  for (int off = 32; off; off >>= 1) s += __shfl_xor(s, off, 64);
  float mean = s * (1.f / 768.f);
  float vs = 0.f;
#pragma unroll
  for (int i = 0; i < 12; ++i) { float d = v[i] - mean; vs += d * d; }
#pragma unroll
  for (int off = 32; off; off >>= 1) vs += __shfl_xor(vs, off, 64);
  float inv = 1.f / sqrtf(vs * (1.f / 768.f) + 1e-6f);
#pragma unroll
  for (int i = 0; i < 12; ++i) {
    int j = lane + i * 64;
    y[(size_t)row * 768 + j] = (OT)((v[i] - mean) * inv * g[j] + bb[j]);
  }
}

__global__ __launch_bounds__(256) void dfc_kernel(
    const float* __restrict__ x, const float* __restrict__ w,
    const float* __restrict__ b0, float* __restrict__ z0, int M) {
  int row = blockIdx.x * 4 + (threadIdx.x >> 6);
  int lane = threadIdx.x & 63;
  if (row >= M) return;
  const float* xr = x + (size_t)row * 768;
  float s = 0.f;
#pragma unroll
  for (int i = 0; i < 12; ++i) s += xr[lane + i * 64] * w[lane + i * 64];
#pragma unroll
  for (int off = 32; off; off >>= 1) s += __shfl_xor(s, off, 64);
  if (lane == 0) z0[row] = s + b0[0];
}

__global__ void head_pe(const float* __restrict__ z0, float* __restrict__ z1) {
  int i = blockIdx.x * 256 + threadIdx.x;
  if (i >= 784) return;
  int b = i / 392, p = i % 392;
  float vals[6], m = 0.f;
#pragma unroll
  for (int t = 0; t < 6; ++t) { vals[t] = z0[(b * 6 + t) * 392 + p]; m += vals[t]; }
  m *= (1.f / 6.f);
  float e = (float)(2 * (p >> 1)) / 392.0f;
  float div = powf(10000.f, -e);
#pragma unroll
  for (int t = 0; t < 6; ++t) {
    float arg = (float)t * div;
    float pe = (p & 1) ? cosf(arg) : sinf(arg);
    z1[(b * 6 + t) * 392 + p] = vals[t] - m + pe;
  }
}

// ---- decoder-head convs ---------------------------------------------------
template <int ID, int IH, int IW, int PD, int PH, int PWA, int OFF, int ST>
__global__ void pad_in(const float* __restrict__ x, float* __restrict__ Xp) {
  int i = blockIdx.x * 256 + threadIdx.x;
  constexpr int total = 12 * PD * PH * PWA;
  if (i >= total) return;
  int px = i % PWA, t1 = i / PWA;
  int py = t1 % PH, t2 = t1 / PH;
  int pz = t2 % PD, c = t2 / PD;
  float v = 0.f;
  int tz = pz - OFF, ty = py - OFF, tx = px - OFF;
  if (tz >= 0 && ty >= 0 && tx >= 0 &&
      (ST == 1 || (((tz | ty | tx) & 1) == 0))) {
    int iz = tz / ST, iy = ty / ST, ix = tx / ST;
    if (iz < ID && iy < IH && ix < IW)
      v = x[((size_t)(c * ID + iz) * IH + iy) * IW + ix];
  }
  Xp[i] = v;
}

template <int PD, int PH, int PWA, int OD, int OH, int OW, int K, int DIL>
__global__ __launch_bounds__(256) void convt4(
    const float* __restrict__ Xp, const float* __restrict__ w,
    const float* __restrict__ bias, float* __restrict__ y) {
  constexpr int P0  = (K - 1) * DIL;
  constexpr int QX  = (OW + 3) / 4;
  constexpr int NLD = (P0 + 4 + 3) / 4;
  int idx = blockIdx.x * 256 + threadIdx.x;
  if (idx >= OD * OH * QX) return;
  int c = blockIdx.y;
  int qx = idx % QX; int t1 = idx / QX;
  int oy = t1 % OH;  int oz = t1 / OH;
  int ox0 = qx * 4;
  const float* xc = Xp + (size_t)c * (PD * PH * PWA);
  const float* wc = w + (c % 6) * (K * K * K);
  const float bv = bias[c % 6];
  float a0 = bv, a1 = bv, a2 = bv, a3 = bv;
  for (int kz = 0; kz < K; ++kz) {
    const int bz = oz + P0 - kz * DIL;
#pragma unroll
    for (int ky = 0; ky < K; ++ky) {
      const int by = oy + P0 - ky * DIL;
      const float* base = xc + ((size_t)bz * PH + by) * PWA + ox0;
      float buf[NLD * 4];
#pragma unroll
      for (int i = 0; i < NLD; ++i)
        *(f32x4*)&buf[i * 4] = *(const f32x4*)(base + i * 4);
      const float* wr = wc + (kz * K + ky) * K;
#pragma unroll
      for (int kx = 0; kx < K; ++kx) {
        const float wv = wr[kx];
        const int j = P0 - kx * DIL;
        a0 += wv * buf[j + 0];
        a1 += wv * buf[j + 1];
        a2 += wv * buf[j + 2];
        a3 += wv * buf[j + 3];
      }
    }
  }
  float* yp = y + (size_t)c * (OD * OH * OW) + ((size_t)oz * OH + oy) * OW + ox0;
  yp[0] = a0;
  if (ox0 + 1 < OW) yp[1] = a1;
  if (ox0 + 2 < OW) yp[2] = a2;
  if (ox0 + 3 < OW) yp[3] = a3;
}

__global__ void head_final(const float* __restrict__ z4, const float* __restrict__ hw,
                           const float* __restrict__ hb, float* __restrict__ out) {
  int idx = blockIdx.x * 256 + threadIdx.x;
  if (idx >= 1613472) return;
  int t = idx % 6, rdx = idx / 6;
  int xx = rdx % 49; rdx /= 49;
  int yy = rdx % 49; rdx /= 49;
  int zz = rdx % 56; int b = rdx / 56;
  const float rz = (float)(47.0 / 56.0), ry = (float)(45.0 / 49.0);
  int iz = (int)((float)zz * rz);
  int iy = (int)((float)yy * ry);
  int ix = (int)((float)xx * ry);
  float v = z4[(((size_t)(b * 6 + t) * 47 + iz) * 45 + iy) * 45 + ix];
  v = v * hw[t] + hb[t];
  v = (v >= 0.f) ? v : (11.0f / 48.0f) * v;
  out[idx] = v;
}

// ---------------------------------------------------------------------------

static inline void launch_gemm(hipStream_t s, const bf16* A, const bf16* B,
                               float* Cf, bf16* Cb, const float* bias,
                               const float* addp, int addmod, int rrelu,
                               int M, int N, int K, int lda, int ldb, int ldc,
                               long long sA, long long sB, long long sC,
                               int nz, int ksplit = 1,
                               bf16* Qo = nullptr, bf16* Ko = nullptr,
                               bf16* Vo = nullptr) {
  dim3 g(CDIV(M, 128), CDIV(N, 64), ksplit > 1 ? ksplit : nz);
  gemm_bt<<<g, 256, 0, s>>>(A, B, Cf, Cb, bias, addp, addmod, rrelu,
                            M, N, K, lda, ldb, ldc, sA, sB, sC, ksplit,
                            Qo, Ko, Vo);
}

extern "C" void kernel_launch(void* const* d_in, const int* in_sizes, int n_in,
                              void* d_out, int out_size, void* d_ws, size_t ws_size,
                              hipStream_t stream) {
  (void)in_sizes; (void)n_in; (void)out_size; (void)ws_size;
  const float* x       = (const float*)d_in[0];
  const float* pconv_w = (const float*)d_in[1];
  const float* pconv_b = (const float*)d_in[2];
  const float* pos_emb = (const float*)d_in[3];
  const float* ln1_g   = (const float*)d_in[4];
  const float* ln1_b   = (const float*)d_in[5];
  const float* qkv_wf  = (const float*)d_in[6];
  const float* qkv_b   = (const float*)d_in[7];
  const float* proj_wf = (const float*)d_in[8];
  const float* proj_b  = (const float*)d_in[9];
  const float* ln2_g   = (const float*)d_in[10];
  const float* ln2_b   = (const float*)d_in[11];
  const float* fc1_wf  = (const float*)d_in[12];
  const float* fc1_b   = (const float*)d_in[13];
  const float* fc2_wf  = (const float*)d_in[14];
  const float* fc2_b   = (const float*)d_in[15];
  const float* normf_g = (const float*)d_in[16];
  const float* normf_b = (const float*)d_in[17];
  const float* dfc_w   = (const float*)d_in[18];
  const float* dfc_b   = (const float*)d_in[19];
  const float* up1_w   = (const float*)d_in[20];
  const float* up1_b   = (const float*)d_in[21];
  const float* up2_w   = (const float*)d_in[22];
  const float* up2_b   = (const float*)d_in[23];
  const float* up3_w   = (const float*)d_in[24];
  const float* up3_b   = (const float*)d_in[25];
  const float* hconv_w = (const float*)d_in[26];
  const float* hconv_b = (const float*)d_in[27];
  float* out = (float*)d_out;

  char* ws = (char*)d_ws;
  size_t off = 0;
  auto alloc = [&](size_t bytes) -> void* {
    void* p = ws + off;
    off += (bytes + 255) & ~(size_t)255;
    return p;
  };
  float* tok   = (float*)alloc(4704UL * 768 * 4);
  bf16* lnout  = (bf16*)alloc(4704UL * 768 * 2);
  bf16* Qb     = (bf16*)alloc(24UL * 2432 * 64 * 2);
  bf16* Kb     = (bf16*)alloc(24UL * 2368 * 64 * 2);
  bf16* VT     = (bf16*)alloc(24UL * 64 * 2368 * 2);
  bf16* attnb  = (bf16*)alloc(4704UL * 768 * 2);
  bf16* hb     = (bf16*)alloc(4704UL * 3072 * 2);
  bf16* Apatch = (bf16*)alloc(4704UL * 352 * 2);
  bf16* Wq     = (bf16*)alloc(2UL * 2304 * 768 * 2);
  bf16* Wp     = (bf16*)alloc(2UL * 768 * 768 * 2);
  bf16* W1     = (bf16*)alloc(2UL * 3072 * 768 * 2);
  bf16* W2     = (bf16*)alloc(2UL * 768 * 3072 * 2);
  bf16* Wpc    = (bf16*)alloc(768UL * 352 * 2);
  float* Opart = (float*)alloc(2UL * 24 * 152 * 1024 * 4);   // 29.9 MB
  float* Lpart = (float*)alloc(2UL * 24 * 152 * 16 * 4);
  float* z0    = (float*)alloc(4704UL * 4);
  float* z1    = (float*)alloc(4704UL * 4);
  float* z2    = (float*)alloc(12UL * 14 * 13 * 13 * 4);
  float* z3    = (float*)alloc(12UL * 31 * 29 * 29 * 4);
  float* z4    = (float*)alloc(12UL * 47 * 45 * 45 * 4);
  float* p1    = (float*)alloc(12UL * 20 * 19 * 24 * 4);
  float* p2    = (float*)alloc(12UL * 35 * 33 * 36 * 4);
  float* p3    = (float*)alloc(12UL * 63 * 61 * 64 * 4);
  float* lnf   = (float*)alloc(4704UL * 768 * 4);

  // ---- weight prep (bf16, vectorized x8) + pad zeroing ----
  cvt_bf16<<<CDIV(3538944 / 8, 256), 256, 0, stream>>>(qkv_wf, Wq, 3538944);
  cvt_bf16<<<CDIV(1179648 / 8, 256), 256, 0, stream>>>(proj_wf, Wp, 1179648);
  cvt_bf16<<<CDIV(4718592 / 8, 256), 256, 0, stream>>>(fc1_wf, W1, 4718592);
  cvt_bf16<<<CDIV(4718592 / 8, 256), 256, 0, stream>>>(fc2_wf, W2, 4718592);
  prep_pconv<<<CDIV(768 * 352, 256), 256, 0, stream>>>(pconv_w, Wpc);
  zero_pads<<<CDIV(122880, 256), 256, 0, stream>>>(Qb, Kb, VT);

  // ---- patch embed (as GEMM) + bias + pos_embed -> tok (fp32) ----
  im2col<<<CDIV(4704 * 352, 256), 256, 0, stream>>>(x, Apatch);
  launch_gemm(stream, Apatch, Wpc, tok, nullptr, pconv_b, pos_emb, 2352, 0,
              4704, 768, 352, 352, 352, 768, 0, 0, 0, 1);

  // ---- transformer layers ----
  for (int i = 0; i < 2; ++i) {
    ln_kernel<bf16><<<1176, 256, 0, stream>>>(tok, ln1_g + i * 768, ln1_b + i * 768, lnout, 4704);
    launch_gemm(stream, lnout, Wq + (size_t)i * 2304 * 768, nullptr, nullptr,
                qkv_b + i * 2304, nullptr, 1, 0,
                4704, 2304, 768, 768, 768, 2304, 0, 0, 0, 1, 1, Qb, Kb, VT);
    flash_attn_split<<<dim3(19, 24, 2), 256, 0, stream>>>(Qb, Kb, VT, Opart, Lpart);
    attn_combine<<<dim3(147, 24), 256, 0, stream>>>(Opart, Lpart, attnb);
    launch_gemm(stream, attnb, Wp + (size_t)i * 768 * 768, tok, nullptr,
                proj_b + i * 768, nullptr, 1, 0,
                4704, 768, 768, 768, 768, 768, 0, 0, 0, 1, 4);
    ln_kernel<bf16><<<1176, 256, 0, stream>>>(tok, ln2_g + i * 768, ln2_b + i * 768, lnout, 4704);
    launch_gemm(stream, lnout, W1 + (size_t)i * 3072 * 768, nullptr, hb,
                fc1_b + i * 3072, nullptr, 1, 1,
                4704, 3072, 768, 768, 768, 3072, 0, 0, 0, 1);
    launch_gemm(stream, hb, W2 + (size_t)i * 768 * 3072, tok, nullptr,
                fc2_b + i * 768, nullptr, 1, 0,
                4704, 768, 3072, 3072, 3072, 768, 0, 0, 0, 1, 4);
  }

  // ---- decoder head (fp32) ----
  ln_kernel<float><<<1176, 256, 0, stream>>>(tok, normf_g, normf_b, lnf, 4704);
  dfc_kernel<<<1176, 256, 0, stream>>>(lnf, dfc_w, dfc_b, z0, 4704);
  head_pe<<<4, 256, 0, stream>>>(z0, z1);

  pad_in<8, 7, 7, 20, 19, 24, 6, 1>
      <<<CDIV(12 * 20 * 19 * 24, 256), 256, 0, stream>>>(z1, p1);
  convt4<20, 19, 24, 14, 13, 13, 7, 1>
      <<<dim3(CDIV(14 * 13 * 4, 256), 12), 256, 0, stream>>>(p1, up1_w, up1_b, z2);
  pad_in<14, 13, 13, 35, 33, 36, 4, 2>
      <<<CDIV(12 * 35 * 33 * 36, 256), 256, 0, stream>>>(z2, p2);
  convt4<35, 33, 36, 31, 29, 29, 5, 1>
      <<<dim3(CDIV(31 * 29 * 8, 256), 12), 256, 0, stream>>>(p2, up2_w, up2_b, z3);
  pad_in<31, 29, 29, 63, 61, 64, 16, 1>
      <<<CDIV(12 * 63 * 61 * 64, 256), 256, 0, stream>>>(z3, p3);
  convt4<63, 61, 64, 47, 45, 45, 9, 2>
      <<<dim3(CDIV(47 * 45 * 12, 256), 12), 256, 0, stream>>>(p3, up3_w, up3_b, z4);

  head_final<<<CDIV(1613472, 256), 256, 0, stream>>>(z4, hconv_w, hconv_b, out);
}

// Round 12
// 1008.974 us; speedup vs baseline: 1.0204x; 1.0022x over previous
//
#include <hip/hip_runtime.h>

// ---------------------------------------------------------------------------
// ScepterVisionTransformer forward on MI355X (gfx950).
// R22:
//  * flash_attn: XCD-grouped grid (T1). R21 counters: FETCH 63.9MB vs ~44MB
//    ideal = 1.45x over-fetch — the 19 blocks sharing one (inst,z)'s K/V
//    round-robin across 8 XCDs, each L2 pulling its own K/V copy from HBM.
//    Launch flat 912 blocks; decode so all 19 blocks of an (inst,z) share
//    one XCD (b%8): g=(b>>3)/19*8+(b&7); inst=g%24; z=g/24; x=(b>>3)%19.
//    Bijective -> perf-only change.
//  * gemm_bt / cvt_bf16 / rest: unchanged from R21 (1011.2us measured).
// ---------------------------------------------------------------------------

#define AS1 __attribute__((address_space(1)))
#define AS3 __attribute__((address_space(3)))

using bf16 = __bf16;
typedef __bf16 bf16x8 __attribute__((ext_vector_type(8)));
typedef float  f32x4  __attribute__((ext_vector_type(4)));

#define CDIV(a, b) (((a) + (b) - 1) / (b))

// DPP row_ror within 16-lane row
template <int SH>
__device__ __forceinline__ float rorf(float x) {
  int i = __builtin_amdgcn_update_dpp(0, __builtin_bit_cast(int, x),
                                      0x120 + SH, 0xF, 0xF, false);
  return __builtin_bit_cast(float, i);
}
__device__ __forceinline__ float rowsum16(float v) {
  v += rorf<1>(v); v += rorf<2>(v); v += rorf<4>(v); v += rorf<8>(v);
  return v;
}

// ---------------------------------------------------------------------------
// Generic GEMM: C(MxN) = A(MxK) * B^T (B stored N-major), bf16 in, fp32 acc.
// Tile 128x64, 4 waves (2M x 2N, each 64x32 out). Reg-staged pipeline:
// tile t+1 in VGPRs, compute t, then write t+1 to the alternate LDS buffer
// and issue loads for t+2. One raw barrier per K-step.
// ksplit>1: partials atomicAdd'ed into Cf (residual-carrying), bias on z==0.
// Qo!=null: qkv-repack epilogue — writes Q/K(scaled)/VT bf16 directly.
// ---------------------------------------------------------------------------
__global__ __launch_bounds__(256) void gemm_bt(
    const bf16* __restrict__ A, const bf16* __restrict__ B,
    float* Cf, bf16* Cb, const float* __restrict__ bias,
    const float* addp, int addmod, int rrelu,
    int M, int N, int K, int lda, int ldb, int ldc,
    long long sA, long long sB, long long sC, int ksplit,
    bf16* __restrict__ Qo, bf16* __restrict__ Ko, bf16* __restrict__ Vo) {
  __shared__ __align__(16) bf16 As[2][128 * 32];   // 8KB x2
  __shared__ __align__(16) bf16 Bs[2][64 * 32];    // 4KB x2  => 24KB total
  const int tid  = threadIdx.x;
  const int lane = tid & 63;
  const int wave = tid >> 6;
  const int wm = wave & 1;
  const int wn = wave >> 1;
  const int q  = lane >> 4;
  const int r  = lane & 15;

  // bijective XCD-aware swizzle of the flat tile index (m204 formula)
  const int nwg = gridDim.x * gridDim.y;
  int flat = blockIdx.y * gridDim.x + blockIdx.x;
  {
    const int qq = nwg >> 3, rr = nwg & 7;
    const int xcd = flat & 7, lid = flat >> 3;
    flat = (xcd < rr ? xcd * (qq + 1) : rr * (qq + 1) + (xcd - rr) * qq) + lid;
  }
  const int tm0 = (flat % gridDim.x) * 128;
  const int tn0 = (flat / gridDim.x) * 64;
  const int z   = blockIdx.z;

  const bf16* Ab = A + (ksplit > 1 ? 0 : (size_t)z * (size_t)sA);
  const bf16* Bb = B + (ksplit > 1 ? 0 : (size_t)z * (size_t)sB);
  int kb = 0, ke = K;
  if (ksplit > 1) {
    const int kc = ((K / ksplit + 31) / 32) * 32;
    kb = z * kc;
    ke = min(kb + kc, K);
  }
  const int nt = (ke - kb + 31) >> 5;

  const int arow0 = min(tm0 + (tid >> 2), M - 1);
  const int arow1 = min(tm0 + (tid >> 2) + 64, M - 1);
  const int brow0 = min(tn0 + (tid >> 2), N - 1);
  const int kcol  = (tid & 3) * 8;
  const bf16* ap0 = Ab + (size_t)arow0 * lda + kcol;
  const bf16* ap1 = Ab + (size_t)arow1 * lda + kcol;
  const bf16* bp0 = Bb + (size_t)brow0 * ldb + kcol;

  f32x4 acc[4][2];
#pragma unroll
  for (int mi = 0; mi < 4; ++mi)
#pragma unroll
    for (int ni = 0; ni < 2; ++ni) acc[mi][ni] = (f32x4){0.f, 0.f, 0.f, 0.f};

  // staged tile registers (one K-step: A 2x16B + B 1x16B per thread)
  bf16x8 rA0, rA1, rB0;
  auto loadT = [&](int t) {
    const int k0 = kb + (t << 5);
    rA0 = *(const bf16x8*)(ap0 + k0);
    rA1 = *(const bf16x8*)(ap1 + k0);
    rB0 = *(const bf16x8*)(bp0 + k0);
  };
  // LDS row-major [rows][32]; thread tid owns elems [tid*8, tid*8+8).
  auto writeT = [&](int buf) {
    *(bf16x8*)&As[buf][tid * 8]        = rA0;
    *(bf16x8*)&As[buf][2048 + tid * 8] = rA1;
    *(bf16x8*)&Bs[buf][tid * 8]        = rB0;
  };

  // prologue: tile 0 -> LDS[0] (exposed once), tile 1 -> regs
  loadT(0);
  writeT(0);
  if (nt > 1) loadT(1);

  for (int t = 0; t < nt; ++t) {
    const int cur = t & 1;
    // own ds ops drained, then block-wide barrier: LDS[cur] (written last
    // iter) visible; all waves done reading LDS[cur^1].
    asm volatile("s_waitcnt lgkmcnt(0)" ::: "memory");
    __builtin_amdgcn_sched_barrier(0);
    __builtin_amdgcn_s_barrier();
    asm volatile("" ::: "memory");
    bf16x8 af[4], bfr[2];
#pragma unroll
    for (int mi = 0; mi < 4; ++mi)
      af[mi] = *(const bf16x8*)&As[cur][(wm * 64 + mi * 16 + r) * 32 + q * 8];
#pragma unroll
    for (int ni = 0; ni < 2; ++ni)
      bfr[ni] = *(const bf16x8*)&Bs[cur][(wn * 32 + ni * 16 + r) * 32 + q * 8];
#pragma unroll
    for (int mi = 0; mi < 4; ++mi)
#pragma unroll
      for (int ni = 0; ni < 2; ++ni)
        acc[mi][ni] = __builtin_amdgcn_mfma_f32_16x16x32_bf16(
            af[mi], bfr[ni], acc[mi][ni], 0, 0, 0);
    // staging BELOW the MFMAs (compute-early/write-late)
    __builtin_amdgcn_sched_barrier(0);
    if (t + 1 < nt) {
      writeT(cur ^ 1);
      if (t + 2 < nt) loadT(t + 2);
    }
  }

  float* cf = Cf ? Cf + (ksplit > 1 ? 0 : (size_t)z * (size_t)sC) : nullptr;
  bf16*  cb = Cb ? Cb + (ksplit > 1 ? 0 : (size_t)z * (size_t)sC) : nullptr;
#pragma unroll
  for (int mi = 0; mi < 4; ++mi) {
    const int row0 = tm0 + wm * 64 + mi * 16 + q * 4;
#pragma unroll
    for (int ni = 0; ni < 2; ++ni) {
      const int col = tn0 + wn * 32 + ni * 16 + r;
      if (col >= N) continue;
      const float bv = bias ? bias[col] : 0.f;
#pragma unroll
      for (int reg = 0; reg < 4; ++reg) {
        const int rr = row0 + reg;
        if (rr >= M) continue;
        if (Qo) {
          const float v = acc[mi][ni][reg] + bv;
          const int which = col / 768;
          const int hh = (col % 768) >> 6;
          const int dd = col & 63;
          const int bb2 = rr / 2352;
          const int ss = rr - bb2 * 2352;
          const int inst = bb2 * 12 + hh;
          if (which == 0)
            Qo[((size_t)inst * 2432 + ss) * 64 + dd] = (bf16)v;
          else if (which == 1)
            Ko[((size_t)inst * 2368 + ss) * 64 + dd] = (bf16)(v * 0.18033688f);
          else
            Vo[((size_t)inst * 64 + dd) * 2368 + ss] = (bf16)v;
        } else if (ksplit > 1) {
          float v = acc[mi][ni][reg];
          if (z == 0) {
            v += bv;
            if (addp) v += addp[(size_t)(rr % addmod) * ldc + col];
          }
          atomicAdd(&cf[(size_t)rr * ldc + col], v);
        } else {
          float v = acc[mi][ni][reg] + bv;
          if (addp) v += addp[(size_t)(rr % addmod) * ldc + col];
          if (rrelu) v = (v >= 0.f) ? v : 0.4f * v;
          if (cf) cf[(size_t)rr * ldc + col] = v;
          else    cb[(size_t)rr * ldc + col] = (bf16)v;
        }
      }
    }
  }
}

// ---------------------------------------------------------------------------
// Flash attention (R21 core + XCD-grouped grid): one wave = 32 Q-rows;
// 2 K-splits. Flat 912-block launch; decode places all 19 x-blocks of an
// (inst,z) on ONE XCD (b%8) so K/V is HBM-fetched once per head-instance
// and L2-hit thereafter. T14 async reg-staged K/V; raw s_barrier +
// lgkmcnt(0) fences; vmcnt never drained; l-reduction deferred.
// LDS 34.8KB -> 4 blocks/CU, full grid co-resident.
// ---------------------------------------------------------------------------
__global__ __launch_bounds__(256) void flash_attn_split(
    const bf16* __restrict__ Qg, const bf16* __restrict__ Kg,
    const bf16* __restrict__ Vt, float* __restrict__ Opart,
    float* __restrict__ Lpart) {
  __shared__ __align__(16) bf16 Kl[64 * 64];   // 8KB, swizzled
  __shared__ __align__(16) bf16 Vl[64 * 64];   // 8KB, swizzled (rows = d)
  __shared__ __align__(16) bf16 Plds[4][2][16 * 72];
  const int tid  = threadIdx.x;
  const int lane = tid & 63;
  const int wave = tid >> 6;
  const int q = lane >> 4, r = lane & 15;

  // XCD-grouped decode: b%8 = XCD (HW round-robin). Group g=(inst,z) -> XCD
  // g%8; its 19 x-blocks occupy b = (b&7 fixed) with consecutive b>>3.
  const int b    = blockIdx.x;          // 0..911
  const int xcd  = b & 7;
  const int rest = b >> 3;              // 0..113
  const int g    = (rest / 19) * 8 + xcd;   // 0..47
  const int xblk = rest % 19;           // 0..18
  const int inst = g % 24;
  const int z    = g / 24;

  const int rt_raw = xblk * 4 + wave;   // 0..75
  const int rt = min(rt_raw, 73);       // clamp: redundant compute, all
                                        // waves participate in barriers
  const int row0 = rt * 32;
  const int ch0 = (z * 37) >> 1;        // 0, 18
  const int ch1 = ((z + 1) * 37) >> 1;  // 18, 37
  const bf16* Qi = Qg + (size_t)inst * 2432 * 64;
  const bf16* Ki = Kg + (size_t)inst * 2368 * 64;
  const bf16* Vi = Vt + (size_t)inst * 64 * 2368;

  bf16x8 qf[2][2];
#pragma unroll
  for (int t = 0; t < 2; ++t) {
    qf[t][0] = *(const bf16x8*)&Qi[(size_t)(row0 + t * 16 + r) * 64 + q * 8];
    qf[t][1] = *(const bf16x8*)&Qi[(size_t)(row0 + t * 16 + r) * 64 + 32 + q * 8];
  }

  f32x4 O[2][4];
  float l[2][4];
#pragma unroll
  for (int t = 0; t < 2; ++t)
#pragma unroll
    for (int i = 0; i < 4; ++i) {
      O[t][i] = (f32x4){0.f, 0.f, 0.f, 0.f};
      l[t][i] = 0.f;
    }

  // ---- T14 reg-staging layout: thread -> (row srow, 16B-unit suc) and
  // (srow+32, suc); global src pre-swizzled so LDS stays linear.
  const int srow = tid >> 3;                 // 0..31
  const int suc  = tid & 7;                  // 0..7
  const int gu   = (suc ^ (srow & 7)) * 8;   // swizzled global unit (elems)
  bf16* const kd0 = &Kl[srow * 64 + suc * 8];
  bf16* const kd1 = &Kl[(srow + 32) * 64 + suc * 8];
  bf16* const vd0 = &Vl[srow * 64 + suc * 8];
  bf16* const vd1 = &Vl[(srow + 32) * 64 + suc * 8];
  const int swz = (r & 7);   // frag-read swizzle key (row & 7 == r & 7)

  bf16x8 kr0, kr1, vr0, vr1;
  auto loadKV = [&](int ch) {
    const size_t col0 = (size_t)ch * 64;
    kr0 = *(const bf16x8*)&Ki[(col0 + srow) * 64 + gu];
    kr1 = *(const bf16x8*)&Ki[(col0 + srow + 32) * 64 + gu];
    vr0 = *(const bf16x8*)&Vi[(size_t)srow * 2368 + col0 + gu];
    vr1 = *(const bf16x8*)&Vi[(size_t)(srow + 32) * 2368 + col0 + gu];
  };

  loadKV(ch0);   // prologue: chunk ch0 in flight
  for (int ch = ch0; ch < ch1; ++ch) {
    // barrier A: all waves done reading LDS for the previous chunk.
    asm volatile("s_waitcnt lgkmcnt(0)" ::: "memory");
    __builtin_amdgcn_sched_barrier(0);
    __builtin_amdgcn_s_barrier();
    asm volatile("" ::: "memory");
    // write staged regs -> LDS (compiler inserts vmcnt waits for reg deps;
    // those loads had a full compute phase to land)
    *(bf16x8*)kd0 = kr0;
    *(bf16x8*)kd1 = kr1;
    *(bf16x8*)vd0 = vr0;
    *(bf16x8*)vd1 = vr1;
    if (ch + 1 < ch1) loadKV(ch + 1);   // issue next chunk, stays in flight
    asm volatile("s_waitcnt lgkmcnt(0)" ::: "memory");
    __builtin_amdgcn_sched_barrier(0);
    // barrier B: all waves' ds_writes visible; vmcnt NOT drained
    __builtin_amdgcn_s_barrier();
    asm volatile("" ::: "memory");

    // frag reads from LDS (swizzled, conflict-free)
    bf16x8 kf0[4], kf1[4], vf0[4], vf1[4];
#pragma unroll
    for (int ct = 0; ct < 4; ++ct) {
      const int krow = ct * 16 + r;
      kf0[ct] = *(const bf16x8*)&Kl[krow * 64 + ((q ^ swz) * 8)];
      kf1[ct] = *(const bf16x8*)&Kl[krow * 64 + (((q + 4) ^ swz) * 8)];
      vf0[ct] = *(const bf16x8*)&Vl[krow * 64 + ((q ^ swz) * 8)];
      vf1[ct] = *(const bf16x8*)&Vl[krow * 64 + (((q + 4) ^ swz) * 8)];
    }

    // S = QK' (scale folded into K), both tiles
    f32x4 s[2][4];
#pragma unroll
    for (int ct = 0; ct < 4; ++ct) {
#pragma unroll
      for (int t = 0; t < 2; ++t) {
        f32x4 a = (f32x4){0.f, 0.f, 0.f, 0.f};
        a = __builtin_amdgcn_mfma_f32_16x16x32_bf16(qf[t][0], kf0[ct], a, 0, 0, 0);
        a = __builtin_amdgcn_mfma_f32_16x16x32_bf16(qf[t][1], kf1[ct], a, 0, 0, 0);
        s[t][ct] = a;
      }
    }
    if (ch == 36) {
      s[0][3] = (f32x4){-1e30f, -1e30f, -1e30f, -1e30f};  // pad cols -> exp2=0
      s[1][3] = (f32x4){-1e30f, -1e30f, -1e30f, -1e30f};
    }
    // softmax numerator: P = exp2(S), no max-shift (scores bounded).
    // l kept as PER-LANE partial; cross-lane rowsum16 deferred to epilogue.
#pragma unroll
    for (int t = 0; t < 2; ++t) {
      float csum[4] = {0.f, 0.f, 0.f, 0.f};
#pragma unroll
      for (int ct = 0; ct < 4; ++ct)
#pragma unroll
        for (int reg = 0; reg < 4; ++reg) {
          float p = exp2f(s[t][ct][reg]);
          s[t][ct][reg] = p;
          csum[reg] += p;
        }
#pragma unroll
      for (int reg = 0; reg < 4; ++reg)
        l[t][reg] += csum[reg];
      bf16* Pw = Plds[wave][t];
#pragma unroll
      for (int ct = 0; ct < 4; ++ct)
#pragma unroll
        for (int reg = 0; reg < 4; ++reg)
          Pw[(q * 4 + reg) * 72 + ct * 16 + r] = (bf16)s[t][ct][reg];
    }
#pragma unroll
    for (int t = 0; t < 2; ++t) {
      const bf16* Pw = Plds[wave][t];
      const bf16x8 pf0 = *(const bf16x8*)&Pw[r * 72 + q * 8];
      const bf16x8 pf1 = *(const bf16x8*)&Pw[r * 72 + 32 + q * 8];
#pragma unroll
      for (int ot = 0; ot < 4; ++ot) {
        O[t][ot] = __builtin_amdgcn_mfma_f32_16x16x32_bf16(pf0, vf0[ot], O[t][ot], 0, 0, 0);
        O[t][ot] = __builtin_amdgcn_mfma_f32_16x16x32_bf16(pf1, vf1[ot], O[t][ot], 0, 0, 0);
      }
    }
  }
  // deferred cross-lane l reduction (8 rowsum16 total, was 8/chunk)
#pragma unroll
  for (int t = 0; t < 2; ++t)
#pragma unroll
    for (int i = 0; i < 4; ++i) l[t][i] = rowsum16(l[t][i]);

  if (rt_raw < 74) {
#pragma unroll
    for (int t = 0; t < 2; ++t) {
      const int p = (z * 24 + inst) * 152 + rt * 2 + t;
      float* Op = Opart + (size_t)p * 1024;
#pragma unroll
      for (int ot = 0; ot < 4; ++ot)
#pragma unroll
        for (int reg = 0; reg < 4; ++reg)
          Op[(q * 4 + reg) * 64 + ot * 16 + r] = O[t][ot][reg];
      if (r == 0) {
#pragma unroll
        for (int reg = 0; reg < 4; ++reg)
          Lpart[(size_t)p * 16 + q * 4 + reg] = l[t][reg];
      }
    }
  }
}

// merge 2 split partials -> attnb bf16: (O1+O2)/(l1+l2)
__global__ __launch_bounds__(256) void attn_combine(
    const float* __restrict__ Opart, const float* __restrict__ Lpart,
    bf16* __restrict__ Og) {
  const int tile = blockIdx.x;   // 147
  const int inst = blockIdx.y;   // 24
  const int bb = inst / 12, hh = inst % 12;
  const int pb = inst * 152 + tile;
#pragma unroll
  for (int i = 0; i < 4; ++i) {
    const int e = threadIdx.x + 256 * i;   // 0..1023
    const int row = e >> 6, col = e & 63;
    const float lsum = Lpart[(size_t)pb * 16 + row] +
                       Lpart[(size_t)(3648 + pb) * 16 + row];
    const float osum = Opart[(size_t)pb * 1024 + e] +
                       Opart[(size_t)(3648 + pb) * 1024 + e];
    Og[(size_t)(bb * 2352 + tile * 16 + row) * 768 + hh * 64 + col] =
        (bf16)(osum / lsum);
  }
}

// --------------------------- small utility kernels -------------------------

__global__ void zero_pads(bf16* __restrict__ Q, bf16* __restrict__ Kb,
                          bf16* __restrict__ VT) {
  int i = blockIdx.x * 256 + threadIdx.x;
  if (i < 122880) {  // 24 inst * 80 rows * 64
    int inst = i / 5120, rem = i % 5120;
    Q[((size_t)inst * 2432 + 2352 + rem / 64) * 64 + (rem & 63)] = (bf16)0.f;
  }
  if (i < 24576) {   // 24 inst * 16 rows * 64
    int inst = i / 1024, rem = i % 1024;
    Kb[((size_t)inst * 2368 + 2352 + rem / 64) * 64 + (rem & 63)] = (bf16)0.f;
  }
  if (i < 24576) {   // 24 inst * 64 d * 16 s
    int inst = i / 1024, rem = i % 1024;
    VT[((size_t)inst * 64 + rem / 16) * 2368 + 2352 + (rem & 15)] = (bf16)0.f;
  }
}

// vectorized fp32 -> bf16 (8 elems/thread); n must be a multiple of 8
__global__ void cvt_bf16(const float* __restrict__ x, bf16* __restrict__ y, int n) {
  int i = (blockIdx.x * 256 + threadIdx.x) * 8;
  if (i >= n) return;
  f32x4 a = *(const f32x4*)(x + i);
  f32x4 b = *(const f32x4*)(x + i + 4);
  bf16x8 o;
  o[0] = (bf16)a[0]; o[1] = (bf16)a[1]; o[2] = (bf16)a[2]; o[3] = (bf16)a[3];
  o[4] = (bf16)b[0]; o[5] = (bf16)b[1]; o[6] = (bf16)b[2]; o[7] = (bf16)b[3];
  *(bf16x8*)(y + i) = o;
}

__global__ void prep_pconv(const float* __restrict__ w, bf16* __restrict__ y) {
  int i = blockIdx.x * 256 + threadIdx.x;
  if (i >= 768 * 352) return;
  int d = i / 352, j = i % 352;
  y[i] = (bf16)(j < 343 ? w[d * 343 + j] : 0.f);
}

__global__ void im2col(const float* __restrict__ x, bf16* __restrict__ A) {
  int i = blockIdx.x * 256 + threadIdx.x;
  if (i >= 4704 * 352) return;
  int j = i % 352, tok = i / 352;
  float v = 0.f;
  if (j < 343) {
    int p = tok % 392, bt = tok / 392;
    int kx = j % 7, ky = (j / 7) % 7, kz = j / 49;
    int px = p % 7, py = (p / 7) % 7, pz = p / 49;
    int zz = pz * 7 + kz, yy = py * 7 + ky, xx = px * 7 + kx;
    v = x[(((size_t)bt * 56 + zz) * 49 + yy) * 49 + xx];
  }
  A[i] = (bf16)v;
}

template <typename OT>
__global__ __launch_bounds__(256) void ln_kernel(
    const float* __restrict__ x, const float* __restrict__ g,
    const float* __restrict__ bb, OT* __restrict__ y, int M) {
  int row = blockIdx.x * 4 + (threadIdx.x >> 6);
  int lane = threadIdx.x & 63;
  if (row >= M) return;
  const float* xr = x + (size_t)row * 768;
  float v[12], s = 0.f;
#pragma unroll
  for (int i = 0; i < 12; ++i) { v[i] = xr[lane + i * 64]; s += v[i]; }
#pragma unroll
  for (int off = 32; off; off >>= 1) s += __shfl_xor(s, off, 64);
  float mean = s * (1.f / 768.f);
  float vs = 0.f;
#pragma unroll
  for (int i = 0; i < 12; ++i) { float d = v[i] - mean; vs += d * d; }
#pragma unroll
  for (int off = 32; off; off >>= 1) vs += __shfl_xor(vs, off, 64);
  float inv = 1.f / sqrtf(vs * (1.f / 768.f) + 1e-6f);
#pragma unroll
  for (int i = 0; i < 12; ++i) {
    int j = lane + i * 64;
    y[(size_t)row * 768 + j] = (OT)((v[i] - mean) * inv * g[j] + bb[j]);
  }
}

__global__ __launch_bounds__(256) void dfc_kernel(
    const float* __restrict__ x, const float* __restrict__ w,
    const float* __restrict__ b0, float* __restrict__ z0, int M) {
  int row = blockIdx.x * 4 + (threadIdx.x >> 6);
  int lane = threadIdx.x & 63;
  if (row >= M) return;
  const float* xr = x + (size_t)row * 768;
  float s = 0.f;
#pragma unroll
  for (int i = 0; i < 12; ++i) s += xr[lane + i * 64] * w[lane + i * 64];
#pragma unroll
  for (int off = 32; off; off >>= 1) s += __shfl_xor(s, off, 64);
  if (lane == 0) z0[row] = s + b0[0];
}

__global__ void head_pe(const float* __restrict__ z0, float* __restrict__ z1) {
  int i = blockIdx.x * 256 + threadIdx.x;
  if (i >= 784) return;
  int b = i / 392, p = i % 392;
  float vals[6], m = 0.f;
#pragma unroll
  for (int t = 0; t < 6; ++t) { vals[t] = z0[(b * 6 + t) * 392 + p]; m += vals[t]; }
  m *= (1.f / 6.f);
  float e = (float)(2 * (p >> 1)) / 392.0f;
  float div = powf(10000.f, -e);
#pragma unroll
  for (int t = 0; t < 6; ++t) {
    float arg = (float)t * div;
    float pe = (p & 1) ? cosf(arg) : sinf(arg);
    z1[(b * 6 + t) * 392 + p] = vals[t] - m + pe;
  }
}

// ---- decoder-head convs ---------------------------------------------------
template <int ID, int IH, int IW, int PD, int PH, int PWA, int OFF, int ST>
__global__ void pad_in(const float* __restrict__ x, float* __restrict__ Xp) {
  int i = blockIdx.x * 256 + threadIdx.x;
  constexpr int total = 12 * PD * PH * PWA;
  if (i >= total) return;
  int px = i % PWA, t1 = i / PWA;
  int py = t1 % PH, t2 = t1 / PH;
  int pz = t2 % PD, c = t2 / PD;
  float v = 0.f;
  int tz = pz - OFF, ty = py - OFF, tx = px - OFF;
  if (tz >= 0 && ty >= 0 && tx >= 0 &&
      (ST == 1 || (((tz | ty | tx) & 1) == 0))) {
    int iz = tz / ST, iy = ty / ST, ix = tx / ST;
    if (iz < ID && iy < IH && ix < IW)
      v = x[((size_t)(c * ID + iz) * IH + iy) * IW + ix];
  }
  Xp[i] = v;
}

template <int PD, int PH, int PWA, int OD, int OH, int OW, int K, int DIL>
__global__ __launch_bounds__(256) void convt4(
    const float* __restrict__ Xp, const float* __restrict__ w,
    const float* __restrict__ bias, float* __restrict__ y) {
  constexpr int P0  = (K - 1) * DIL;
  constexpr int QX  = (OW + 3) / 4;
  constexpr int NLD = (P0 + 4 + 3) / 4;
  int idx = blockIdx.x * 256 + threadIdx.x;
  if (idx >= OD * OH * QX) return;
  int c = blockIdx.y;
  int qx = idx % QX; int t1 = idx / QX;
  int oy = t1 % OH;  int oz = t1 / OH;
  int ox0 = qx * 4;
  const float* xc = Xp + (size_t)c * (PD * PH * PWA);
  const float* wc = w + (c % 6) * (K * K * K);
  const float bv = bias[c % 6];
  float a0 = bv, a1 = bv, a2 = bv, a3 = bv;
  for (int kz = 0; kz < K; ++kz) {
    const int bz = oz + P0 - kz * DIL;
#pragma unroll
    for (int ky = 0; ky < K; ++ky) {
      const int by = oy + P0 - ky * DIL;
      const float* base = xc + ((size_t)bz * PH + by) * PWA + ox0;
      float buf[NLD * 4];
#pragma unroll
      for (int i = 0; i < NLD; ++i)
        *(f32x4*)&buf[i * 4] = *(const f32x4*)(base + i * 4);
      const float* wr = wc + (kz * K + ky) * K;
#pragma unroll
      for (int kx = 0; kx < K; ++kx) {
        const float wv = wr[kx];
        const int j = P0 - kx * DIL;
        a0 += wv * buf[j + 0];
        a1 += wv * buf[j + 1];
        a2 += wv * buf[j + 2];
        a3 += wv * buf[j + 3];
      }
    }
  }
  float* yp = y + (size_t)c * (OD * OH * OW) + ((size_t)oz * OH + oy) * OW + ox0;
  yp[0] = a0;
  if (ox0 + 1 < OW) yp[1] = a1;
  if (ox0 + 2 < OW) yp[2] = a2;
  if (ox0 + 3 < OW) yp[3] = a3;
}

__global__ void head_final(const float* __restrict__ z4, const float* __restrict__ hw,
                           const float* __restrict__ hb, float* __restrict__ out) {
  int idx = blockIdx.x * 256 + threadIdx.x;
  if (idx >= 1613472) return;
  int t = idx % 6, rdx = idx / 6;
  int xx = rdx % 49; rdx /= 49;
  int yy = rdx % 49; rdx /= 49;
  int zz = rdx % 56; int b = rdx / 56;
  const float rz = (float)(47.0 / 56.0), ry = (float)(45.0 / 49.0);
  int iz = (int)((float)zz * rz);
  int iy = (int)((float)yy * ry);
  int ix = (int)((float)xx * ry);
  float v = z4[(((size_t)(b * 6 + t) * 47 + iz) * 45 + iy) * 45 + ix];
  v = v * hw[t] + hb[t];
  v = (v >= 0.f) ? v : (11.0f / 48.0f) * v;
  out[idx] = v;
}

// ---------------------------------------------------------------------------

static inline void launch_gemm(hipStream_t s, const bf16* A, const bf16* B,
                               float* Cf, bf16* Cb, const float* bias,
                               const float* addp, int addmod, int rrelu,
                               int M, int N, int K, int lda, int ldb, int ldc,
                               long long sA, long long sB, long long sC,
                               int nz, int ksplit = 1,
                               bf16* Qo = nullptr, bf16* Ko = nullptr,
                               bf16* Vo = nullptr) {
  dim3 g(CDIV(M, 128), CDIV(N, 64), ksplit > 1 ? ksplit : nz);
  gemm_bt<<<g, 256, 0, s>>>(A, B, Cf, Cb, bias, addp, addmod, rrelu,
                            M, N, K, lda, ldb, ldc, sA, sB, sC, ksplit,
                            Qo, Ko, Vo);
}

extern "C" void kernel_launch(void* const* d_in, const int* in_sizes, int n_in,
                              void* d_out, int out_size, void* d_ws, size_t ws_size,
                              hipStream_t stream) {
  (void)in_sizes; (void)n_in; (void)out_size; (void)ws_size;
  const float* x       = (const float*)d_in[0];
  const float* pconv_w = (const float*)d_in[1];
  const float* pconv_b = (const float*)d_in[2];
  const float* pos_emb = (const float*)d_in[3];
  const float* ln1_g   = (const float*)d_in[4];
  const float* ln1_b   = (const float*)d_in[5];
  const float* qkv_wf  = (const float*)d_in[6];
  const float* qkv_b   = (const float*)d_in[7];
  const float* proj_wf = (const float*)d_in[8];
  const float* proj_b  = (const float*)d_in[9];
  const float* ln2_g   = (const float*)d_in[10];
  const float* ln2_b   = (const float*)d_in[11];
  const float* fc1_wf  = (const float*)d_in[12];
  const float* fc1_b   = (const float*)d_in[13];
  const float* fc2_wf  = (const float*)d_in[14];
  const float* fc2_b   = (const float*)d_in[15];
  const float* normf_g = (const float*)d_in[16];
  const float* normf_b = (const float*)d_in[17];
  const float* dfc_w   = (const float*)d_in[18];
  const float* dfc_b   = (const float*)d_in[19];
  const float* up1_w   = (const float*)d_in[20];
  const float* up1_b   = (const float*)d_in[21];
  const float* up2_w   = (const float*)d_in[22];
  const float* up2_b   = (const float*)d_in[23];
  const float* up3_w   = (const float*)d_in[24];
  const float* up3_b   = (const float*)d_in[25];
  const float* hconv_w = (const float*)d_in[26];
  const float* hconv_b = (const float*)d_in[27];
  float* out = (float*)d_out;

  char* ws = (char*)d_ws;
  size_t off = 0;
  auto alloc = [&](size_t bytes) -> void* {
    void* p = ws + off;
    off += (bytes + 255) & ~(size_t)255;
    return p;
  };
  float* tok   = (float*)alloc(4704UL * 768 * 4);
  bf16* lnout  = (bf16*)alloc(4704UL * 768 * 2);
  bf16* Qb     = (bf16*)alloc(24UL * 2432 * 64 * 2);
  bf16* Kb     = (bf16*)alloc(24UL * 2368 * 64 * 2);
  bf16* VT     = (bf16*)alloc(24UL * 64 * 2368 * 2);
  bf16* attnb  = (bf16*)alloc(4704UL * 768 * 2);
  bf16* hb     = (bf16*)alloc(4704UL * 3072 * 2);
  bf16* Apatch = (bf16*)alloc(4704UL * 352 * 2);
  bf16* Wq     = (bf16*)alloc(2UL * 2304 * 768 * 2);
  bf16* Wp     = (bf16*)alloc(2UL * 768 * 768 * 2);
  bf16* W1     = (bf16*)alloc(2UL * 3072 * 768 * 2);
  bf16* W2     = (bf16*)alloc(2UL * 768 * 3072 * 2);
  bf16* Wpc    = (bf16*)alloc(768UL * 352 * 2);
  float* Opart = (float*)alloc(2UL * 24 * 152 * 1024 * 4);   // 29.9 MB
  float* Lpart = (float*)alloc(2UL * 24 * 152 * 16 * 4);
  float* z0    = (float*)alloc(4704UL * 4);
  float* z1    = (float*)alloc(4704UL * 4);
  float* z2    = (float*)alloc(12UL * 14 * 13 * 13 * 4);
  float* z3    = (float*)alloc(12UL * 31 * 29 * 29 * 4);
  float* z4    = (float*)alloc(12UL * 47 * 45 * 45 * 4);
  float* p1    = (float*)alloc(12UL * 20 * 19 * 24 * 4);
  float* p2    = (float*)alloc(12UL * 35 * 33 * 36 * 4);
  float* p3    = (float*)alloc(12UL * 63 * 61 * 64 * 4);
  float* lnf   = (float*)alloc(4704UL * 768 * 4);

  // ---- weight prep (bf16, vectorized x8) + pad zeroing ----
  cvt_bf16<<<CDIV(3538944 / 8, 256), 256, 0, stream>>>(qkv_wf, Wq, 3538944);
  cvt_bf16<<<CDIV(1179648 / 8, 256), 256, 0, stream>>>(proj_wf, Wp, 1179648);
  cvt_bf16<<<CDIV(4718592 / 8, 256), 256, 0, stream>>>(fc1_wf, W1, 4718592);
  cvt_bf16<<<CDIV(4718592 / 8, 256), 256, 0, stream>>>(fc2_wf, W2, 4718592);
  prep_pconv<<<CDIV(768 * 352, 256), 256, 0, stream>>>(pconv_w, Wpc);
  zero_pads<<<CDIV(122880, 256), 256, 0, stream>>>(Qb, Kb, VT);

  // ---- patch embed (as GEMM) + bias + pos_embed -> tok (fp32) ----
  im2col<<<CDIV(4704 * 352, 256), 256, 0, stream>>>(x, Apatch);
  launch_gemm(stream, Apatch, Wpc, tok, nullptr, pconv_b, pos_emb, 2352, 0,
              4704, 768, 352, 352, 352, 768, 0, 0, 0, 1);

  // ---- transformer layers ----
  for (int i = 0; i < 2; ++i) {
    ln_kernel<bf16><<<1176, 256, 0, stream>>>(tok, ln1_g + i * 768, ln1_b + i * 768, lnout, 4704);
    launch_gemm(stream, lnout, Wq + (size_t)i * 2304 * 768, nullptr, nullptr,
                qkv_b + i * 2304, nullptr, 1, 0,
                4704, 2304, 768, 768, 768, 2304, 0, 0, 0, 1, 1, Qb, Kb, VT);
    flash_attn_split<<<dim3(912), 256, 0, stream>>>(Qb, Kb, VT, Opart, Lpart);
    attn_combine<<<dim3(147, 24), 256, 0, stream>>>(Opart, Lpart, attnb);
    launch_gemm(stream, attnb, Wp + (size_t)i * 768 * 768, tok, nullptr,
                proj_b + i * 768, nullptr, 1, 0,
                4704, 768, 768, 768, 768, 768, 0, 0, 0, 1, 4);
    ln_kernel<bf16><<<1176, 256, 0, stream>>>(tok, ln2_g + i * 768, ln2_b + i * 768, lnout, 4704);
    launch_gemm(stream, lnout, W1 + (size_t)i * 3072 * 768, nullptr, hb,
                fc1_b + i * 3072, nullptr, 1, 1,
                4704, 3072, 768, 768, 768, 3072, 0, 0, 0, 1);
    launch_gemm(stream, hb, W2 + (size_t)i * 768 * 3072, tok, nullptr,
                fc2_b + i * 768, nullptr, 1, 0,
                4704, 768, 3072, 3072, 3072, 768, 0, 0, 0, 1, 4);
  }

  // ---- decoder head (fp32) ----
  ln_kernel<float><<<1176, 256, 0, stream>>>(tok, normf_g, normf_b, lnf, 4704);
  dfc_kernel<<<1176, 256, 0, stream>>>(lnf, dfc_w, dfc_b, z0, 4704);
  head_pe<<<4, 256, 0, stream>>>(z0, z1);

  pad_in<8, 7, 7, 20, 19, 24, 6, 1>
      <<<CDIV(12 * 20 * 19 * 24, 256), 256, 0, stream>>>(z1, p1);
  convt4<20, 19, 24, 14, 13, 13, 7, 1>
      <<<dim3(CDIV(14 * 13 * 4, 256), 12), 256, 0, stream>>>(p1, up1_w, up1_b, z2);
  pad_in<14, 13, 13, 35, 33, 36, 4, 2>
      <<<CDIV(12 * 35 * 33 * 36, 256), 256, 0, stream>>>(z2, p2);
  convt4<35, 33, 36, 31, 29, 29, 5, 1>
      <<<dim3(CDIV(31 * 29 * 8, 256), 12), 256, 0, stream>>>(p2, up2_w, up2_b, z3);
  pad_in<31, 29, 29, 63, 61, 64, 16, 1>
      <<<CDIV(12 * 63 * 61 * 64, 256), 256, 0, stream>>>(z3, p3);
  convt4<63, 61, 64, 47, 45, 45, 9, 2>
      <<<dim3(CDIV(47 * 45 * 12, 256), 12), 256, 0, stream>>>(p3, up3_w, up3_b, z4);

  head_final<<<CDIV(1613472, 256), 256, 0, stream>>>(z4, hconv_w, hconv_b, out);
}